// Round 3
// baseline (4661.660 us; speedup 1.0000x reference)
//
#include <hip/hip_runtime.h>
#include <math.h>

// Problem constants
#define NXc 128
#define NQc 128
#define NUc 64
#define NYc 64
#define BATCHc 200000

// workspace layout (float offsets); total ~459 KB
#define WS_P    0
#define WS_Y    16384
#define WS_R    32768
#define WS_A    49152
#define WS_B1   65536
#define WS_C1   81920
#define WS_D11  98304

__device__ __forceinline__ float fast_tanh(float x) {
  float e = __expf(2.0f * x);
  return 1.0f - 2.0f / (e + 1.0f);
}

// K1: compute P, Y, R, C1, D11 into ws. 5*16384 elements, one thread each.
__global__ __launch_bounds__(256) void k1_params(
    const float* __restrict__ Pstar, const float* __restrict__ Chi,
    const float* __restrict__ Y1, const float* __restrict__ X,
    float* __restrict__ ws)
{
  int gid = blockIdx.x * 256 + threadIdx.x;
  int mat = gid >> 14;
  int idx = gid & 16383;
  int i = idx >> 7, j = idx & 127;
  if (mat == 0) {
    // P = 0.5*Pstar@Pstar.T + eps I
    float s = 0.f;
    for (int k = 0; k < 128; ++k) s = fmaf(Pstar[i*128+k], Pstar[j*128+k], s);
    ws[WS_P + idx] = 0.5f*s + (i==j ? 0.01f : 0.f);
  } else if (mat == 1) {
    // Y = -0.5*(H1 + Y1 - Y1^T), H1 = (X X^T)[:128,:128] + eps I
    float s = 0.f;
    for (int k = 0; k < 256; ++k) s = fmaf(X[i*256+k], X[j*256+k], s);
    float h1 = s + (i==j ? 0.01f : 0.f);
    ws[WS_Y + idx] = -0.5f*(h1 + Y1[i*128+j] - Y1[j*128+i]);
  } else if (mat == 2) {
    // R = -H2 - Chi, H2[i][j] = sum_k X[i,k] X[128+j,k]
    float s = 0.f;
    for (int k = 0; k < 256; ++k) s = fmaf(X[i*256+k], X[(128+j)*256+k], s);
    ws[WS_R + idx] = -s - Chi[i*128+j];
  } else if (mat == 3) {
    // C1[q][x] = Chi[x][q] / lam[q];  lam[q] = 0.5*(||X[128+q]||^2 + eps)
    float lam = 0.f;
    for (int k = 0; k < 256; ++k) { float v = X[(128+i)*256+k]; lam = fmaf(v, v, lam); }
    lam = 0.5f*(lam + 0.01f);
    ws[WS_C1 + idx] = Chi[j*128+i] / lam;
  } else {
    // D11[i][j] = (j<i) ? -H4[i][j]/lam[i] : 0
    float lam = 0.f, s = 0.f;
    for (int k = 0; k < 256; ++k) {
      float vi = X[(128+i)*256+k];
      lam = fmaf(vi, vi, lam);
      s = fmaf(vi, X[(128+j)*256+k], s);
    }
    lam = 0.5f*(lam + 0.01f);
    ws[WS_D11 + idx] = (j < i) ? (-s / lam) : 0.f;
  }
}

// K2: in-place Gauss-Jordan inversion of P (SPD, no pivoting), 1 block.
__global__ __launch_bounds__(256) void k2_invert(float* __restrict__ ws)
{
  __shared__ float Pls[128*130];
  __shared__ float fcol[128];
  const int t = threadIdx.x;
  for (int idx = t; idx < 16384; idx += 256) {
    int i = idx >> 7, j = idx & 127;
    Pls[i*130 + j] = ws[WS_P + idx];
  }
  __syncthreads();
  for (int k = 0; k < 128; ++k) {
    // S0: snapshot pivot + column k
    float pinv = 1.0f / Pls[k*130+k];
    if (t < 128) fcol[t] = Pls[t*130+k];
    __syncthreads();
    // S1: scale row k; set column k to final values
    if (t < 128) {
      int j = t;
      if (j == k) Pls[k*130+j] = pinv;
      else        Pls[k*130+j] *= pinv;
    } else {
      int i = t - 128;
      if (i != k) Pls[i*130+k] = -fcol[i]*pinv;
    }
    __syncthreads();
    // S2: rank-1 update of the rest
    for (int idx = t; idx < 16384; idx += 256) {
      int i = idx >> 7, j = idx & 127;
      if (i != k && j != k) Pls[i*130+j] = fmaf(-fcol[i], Pls[k*130+j], Pls[i*130+j]);
    }
    __syncthreads();
  }
  for (int idx = t; idx < 16384; idx += 256) {
    int i = idx >> 7, j = idx & 127;
    ws[WS_P + idx] = Pls[i*130+j];
  }
}

// K3: A = Pinv@Y, B1 = Pinv@R. 128 blocks (one output row each), 256 threads.
__global__ __launch_bounds__(256) void k3_solve(float* __restrict__ ws)
{
  const int i = blockIdx.x;
  const int t = threadIdx.x;
  const int j = t & 127;
  const int which = t >> 7;
  const float* Pinv = ws + WS_P;
  const float* Src  = ws + (which ? WS_R : WS_Y);
  float* Dst        = ws + (which ? WS_B1 : WS_A);
  float s = 0.f;
  for (int k = 0; k < 128; ++k) s = fmaf(Pinv[i*128+k], Src[k*128+j], s);
  Dst[i*128+j] = s;
}

// K4: fused forward over a 64-row batch tile per block. 256 threads = 4 waves.
// thread role in GEMM phases: r = tid&63 (row), g = tid>>6 (column group, stride 4)
// recurrence: each wave handles 16 rows, 4 lanes per row.
__global__ __launch_bounds__(256) void k4_forward(
    const float* __restrict__ xi, const float* __restrict__ u,
    const float* __restrict__ ws,
    const float* __restrict__ B2, const float* __restrict__ D12,
    const float* __restrict__ C2, const float* __restrict__ D21,
    const float* __restrict__ D22,
    float* __restrict__ out)
{
  __shared__ float s_bw[64*133];  // base, overlaid with w during recurrence
  __shared__ float s_u[64*65];
  __shared__ float s_xc[64*33];

  const float* Am   = ws + WS_A;
  const float* B1m  = ws + WS_B1;
  const float* C1m  = ws + WS_C1;
  const float* D11m = ws + WS_D11;

  const int tid = threadIdx.x;
  const int r = tid & 63;
  const int g = __builtin_amdgcn_readfirstlane(tid >> 6);  // wave-uniform
  const int row0 = blockIdx.x * 64;

  // stage u tile (coalesced)
  for (int idx = tid; idx < 64*64; idx += 256) {
    int rr = idx >> 6, cc = idx & 63;
    s_u[rr*65 + cc] = u[(row0 + rr)*64 + cc];
  }

  // ---- base = xi@C1^T + u@D12^T ----
  float acc[32];
  #pragma unroll
  for (int q = 0; q < 32; ++q) acc[q] = 0.f;

  for (int kk = 0; kk < 4; ++kk) {
    __syncthreads();
    for (int idx = tid; idx < 64*32; idx += 256) {
      int rr = idx >> 5, cc = idx & 31;
      s_xc[rr*33 + cc] = xi[(row0 + rr)*128 + kk*32 + cc];
    }
    __syncthreads();
    float xr[32];
    #pragma unroll
    for (int k2 = 0; k2 < 32; ++k2) xr[k2] = s_xc[r*33 + k2];
    #pragma unroll
    for (int q = 0; q < 32; ++q) {
      const float* cp = C1m + (g + 4*q)*128 + kk*32;
      #pragma unroll
      for (int k2 = 0; k2 < 32; ++k2) acc[q] = fmaf(xr[k2], cp[k2], acc[q]);
    }
  }
  for (int m = 0; m < 64; ++m) {
    float uv = s_u[r*65 + m];
    #pragma unroll
    for (int q = 0; q < 32; ++q) acc[q] = fmaf(uv, D12[(g + 4*q)*64 + m], acc[q]);
  }
  #pragma unroll
  for (int q = 0; q < 32; ++q) s_bw[r*133 + (g + 4*q)] = acc[q];
  __syncthreads();

  // ---- recurrence: w[i] = tanh(base[i] + sum_{j<i} D11[i][j]*w[j]) ----
  {
    const int l = tid & 63;
    const int c = l & 3;           // 4 lanes per row
    const int rr = g*16 + (l >> 2);
    const int rb = rr*133;
    for (int i = 0; i < 128; ++i) {
      float p0 = 0.f;
      for (int j = c; j < i; j += 4)
        p0 = fmaf(D11m[i*128 + j], s_bw[rb + j], p0);
      p0 += __shfl_xor(p0, 1);
      p0 += __shfl_xor(p0, 2);
      float x = s_bw[rb + i] + p0;   // base, read before overwrite
      float v = fast_tanh(x);
      if (c == 0) s_bw[rb + i] = v;  // wave-synchronous, DS in-order
    }
  }
  __syncthreads();

  // ---- xi_dot = xi@A^T + w@B1^T + u@B2^T ; yi = xi@C2^T + w@D21^T + u@D22^T ----
  float ax[32], ay[16];
  #pragma unroll
  for (int q = 0; q < 32; ++q) ax[q] = 0.f;
  #pragma unroll
  for (int q = 0; q < 16; ++q) ay[q] = 0.f;

  for (int j = 0; j < 128; ++j) {
    float wv = s_bw[r*133 + j];
    #pragma unroll
    for (int q = 0; q < 32; ++q) ax[q] = fmaf(wv, B1m[(g + 4*q)*128 + j], ax[q]);
    #pragma unroll
    for (int q = 0; q < 16; ++q) ay[q] = fmaf(wv, D21[(g + 4*q)*128 + j], ay[q]);
  }
  for (int m = 0; m < 64; ++m) {
    float uv = s_u[r*65 + m];
    #pragma unroll
    for (int q = 0; q < 32; ++q) ax[q] = fmaf(uv, B2[(g + 4*q)*64 + m], ax[q]);
    #pragma unroll
    for (int q = 0; q < 16; ++q) ay[q] = fmaf(uv, D22[(g + 4*q)*64 + m], ay[q]);
  }
  for (int kk = 0; kk < 4; ++kk) {
    __syncthreads();
    for (int idx = tid; idx < 64*32; idx += 256) {
      int rr = idx >> 5, cc = idx & 31;
      s_xc[rr*33 + cc] = xi[(row0 + rr)*128 + kk*32 + cc];
    }
    __syncthreads();
    float xr[32];
    #pragma unroll
    for (int k2 = 0; k2 < 32; ++k2) xr[k2] = s_xc[r*33 + k2];
    #pragma unroll
    for (int q = 0; q < 32; ++q) {
      const float* ap = Am + (g + 4*q)*128 + kk*32;
      #pragma unroll
      for (int k2 = 0; k2 < 32; ++k2) ax[q] = fmaf(xr[k2], ap[k2], ax[q]);
    }
    #pragma unroll
    for (int q = 0; q < 16; ++q) {
      const float* cp = C2 + (g + 4*q)*128 + kk*32;
      #pragma unroll
      for (int k2 = 0; k2 < 32; ++k2) ay[q] = fmaf(xr[k2], cp[k2], ay[q]);
    }
  }

  #pragma unroll
  for (int q = 0; q < 32; ++q)
    out[(row0 + r)*128 + (g + 4*q)] = ax[q];
  const int yoff = BATCHc * 128;
  #pragma unroll
  for (int q = 0; q < 16; ++q)
    out[yoff + (row0 + r)*64 + (g + 4*q)] = ay[q];
}

extern "C" void kernel_launch(void* const* d_in, const int* in_sizes, int n_in,
                              void* d_out, int out_size, void* d_ws, size_t ws_size,
                              hipStream_t stream) {
  // inputs: 0:t 1:xi 2:u 3:Pstar 4:Chi 5:Y1 6:X 7:B2 8:D12 9:C2 10:D21 11:D22
  const float* xi    = (const float*)d_in[1];
  const float* u     = (const float*)d_in[2];
  const float* Pstar = (const float*)d_in[3];
  const float* Chi   = (const float*)d_in[4];
  const float* Y1    = (const float*)d_in[5];
  const float* X     = (const float*)d_in[6];
  const float* B2    = (const float*)d_in[7];
  const float* D12   = (const float*)d_in[8];
  const float* C2    = (const float*)d_in[9];
  const float* D21   = (const float*)d_in[10];
  const float* D22   = (const float*)d_in[11];
  float* out = (float*)d_out;
  float* ws  = (float*)d_ws;   // uses ~459 KB

  k1_params<<<320, 256, 0, stream>>>(Pstar, Chi, Y1, X, ws);
  k2_invert<<<1, 256, 0, stream>>>(ws);
  k3_solve<<<128, 256, 0, stream>>>(ws);
  k4_forward<<<(BATCHc/64), 256, 0, stream>>>(xi, u, ws, B2, D12, C2, D21, D22, out);
}

// Round 4
// 4655.264 us; speedup vs baseline: 1.0014x; 1.0014x over previous
//
#include <hip/hip_runtime.h>
#include <math.h>

// Problem constants
#define NXc 128
#define NQc 128
#define NUc 64
#define NYc 64
#define BATCHc 200000

// workspace layout (float offsets); total ~459 KB
#define WS_P    0
#define WS_Y    16384
#define WS_R    32768
#define WS_A    49152
#define WS_B1   65536
#define WS_C1   81920
#define WS_D11  98304

__device__ __forceinline__ float fast_tanh(float x) {
  float e = __expf(2.0f * x);
  return 1.0f - 2.0f / (e + 1.0f);
}

// K1: compute P, Y, R, C1, D11 into ws. 5*16384 elements, one thread each.
__global__ __launch_bounds__(256) void k1_params(
    const float* __restrict__ Pstar, const float* __restrict__ Chi,
    const float* __restrict__ Y1, const float* __restrict__ X,
    float* __restrict__ ws)
{
  int gid = blockIdx.x * 256 + threadIdx.x;
  int mat = gid >> 14;
  int idx = gid & 16383;
  int i = idx >> 7, j = idx & 127;
  if (mat == 0) {
    // P = 0.5*Pstar@Pstar.T + eps I
    float s = 0.f;
    for (int k = 0; k < 128; ++k) s = fmaf(Pstar[i*128+k], Pstar[j*128+k], s);
    ws[WS_P + idx] = 0.5f*s + (i==j ? 0.01f : 0.f);
  } else if (mat == 1) {
    // Y = -0.5*(H1 + Y1 - Y1^T), H1 = (X X^T)[:128,:128] + eps I
    float s = 0.f;
    for (int k = 0; k < 256; ++k) s = fmaf(X[i*256+k], X[j*256+k], s);
    float h1 = s + (i==j ? 0.01f : 0.f);
    ws[WS_Y + idx] = -0.5f*(h1 + Y1[i*128+j] - Y1[j*128+i]);
  } else if (mat == 2) {
    // R = -H2 - Chi, H2[i][j] = sum_k X[i,k] X[128+j,k]
    float s = 0.f;
    for (int k = 0; k < 256; ++k) s = fmaf(X[i*256+k], X[(128+j)*256+k], s);
    ws[WS_R + idx] = -s - Chi[i*128+j];
  } else if (mat == 3) {
    // C1[q][x] = Chi[x][q] / lam[q];  lam[q] = 0.5*(||X[128+q]||^2 + eps)
    float lam = 0.f;
    for (int k = 0; k < 256; ++k) { float v = X[(128+i)*256+k]; lam = fmaf(v, v, lam); }
    lam = 0.5f*(lam + 0.01f);
    ws[WS_C1 + idx] = Chi[j*128+i] / lam;
  } else {
    // D11[i][j] = (j<i) ? -H4[i][j]/lam[i] : 0
    float lam = 0.f, s = 0.f;
    for (int k = 0; k < 256; ++k) {
      float vi = X[(128+i)*256+k];
      lam = fmaf(vi, vi, lam);
      s = fmaf(vi, X[(128+j)*256+k], s);
    }
    lam = 0.5f*(lam + 0.01f);
    ws[WS_D11 + idx] = (j < i) ? (-s / lam) : 0.f;
  }
}

// K2: in-place Gauss-Jordan inversion of P (SPD, no pivoting), 1 block.
__global__ __launch_bounds__(256) void k2_invert(float* __restrict__ ws)
{
  __shared__ float Pls[128*130];
  __shared__ float fcol[128];
  const int t = threadIdx.x;
  for (int idx = t; idx < 16384; idx += 256) {
    int i = idx >> 7, j = idx & 127;
    Pls[i*130 + j] = ws[WS_P + idx];
  }
  __syncthreads();
  for (int k = 0; k < 128; ++k) {
    // S0: snapshot pivot + column k
    float pinv = 1.0f / Pls[k*130+k];
    if (t < 128) fcol[t] = Pls[t*130+k];
    __syncthreads();
    // S1: scale row k; set column k to final values
    if (t < 128) {
      int j = t;
      if (j == k) Pls[k*130+j] = pinv;
      else        Pls[k*130+j] *= pinv;
    } else {
      int i = t - 128;
      if (i != k) Pls[i*130+k] = -fcol[i]*pinv;
    }
    __syncthreads();
    // S2: rank-1 update of the rest
    for (int idx = t; idx < 16384; idx += 256) {
      int i = idx >> 7, j = idx & 127;
      if (i != k && j != k) Pls[i*130+j] = fmaf(-fcol[i], Pls[k*130+j], Pls[i*130+j]);
    }
    __syncthreads();
  }
  for (int idx = t; idx < 16384; idx += 256) {
    int i = idx >> 7, j = idx & 127;
    ws[WS_P + idx] = Pls[i*130+j];
  }
}

// K3: A = Pinv@Y, B1 = Pinv@R. 128 blocks (one output row each), 256 threads.
__global__ __launch_bounds__(256) void k3_solve(float* __restrict__ ws)
{
  const int i = blockIdx.x;
  const int t = threadIdx.x;
  const int j = t & 127;
  const int which = t >> 7;
  const float* Pinv = ws + WS_P;
  const float* Src  = ws + (which ? WS_R : WS_Y);
  float* Dst        = ws + (which ? WS_B1 : WS_A);
  float s = 0.f;
  for (int k = 0; k < 128; ++k) s = fmaf(Pinv[i*128+k], Src[k*128+j], s);
  Dst[i*128+j] = s;
}

// K4: fused forward over a 64-row batch tile per block. 256 threads = 4 waves.
// thread role in GEMM phases: r = tid&63 (row), g = tid>>6 (column group, stride 4)
// recurrence: each wave handles 16 rows, 4 lanes per row.
__global__ __launch_bounds__(256) void k4_forward(
    const float* __restrict__ xi, const float* __restrict__ u,
    const float* __restrict__ ws,
    const float* __restrict__ B2, const float* __restrict__ D12,
    const float* __restrict__ C2, const float* __restrict__ D21,
    const float* __restrict__ D22,
    float* __restrict__ out)
{
  __shared__ float s_bw[64*133];  // base, overlaid with w during recurrence
  __shared__ float s_u[64*65];
  __shared__ float s_xc[64*33];

  const float* Am   = ws + WS_A;
  const float* B1m  = ws + WS_B1;
  const float* C1m  = ws + WS_C1;
  const float* D11m = ws + WS_D11;

  const int tid = threadIdx.x;
  const int r = tid & 63;
  const int g = __builtin_amdgcn_readfirstlane(tid >> 6);  // wave-uniform
  const int row0 = blockIdx.x * 64;

  // stage u tile (coalesced)
  for (int idx = tid; idx < 64*64; idx += 256) {
    int rr = idx >> 6, cc = idx & 63;
    s_u[rr*65 + cc] = u[(row0 + rr)*64 + cc];
  }

  // ---- base = xi@C1^T + u@D12^T ----
  float acc[32];
  #pragma unroll
  for (int q = 0; q < 32; ++q) acc[q] = 0.f;

  for (int kk = 0; kk < 4; ++kk) {
    __syncthreads();
    for (int idx = tid; idx < 64*32; idx += 256) {
      int rr = idx >> 5, cc = idx & 31;
      s_xc[rr*33 + cc] = xi[(row0 + rr)*128 + kk*32 + cc];
    }
    __syncthreads();
    float xr[32];
    #pragma unroll
    for (int k2 = 0; k2 < 32; ++k2) xr[k2] = s_xc[r*33 + k2];
    #pragma unroll
    for (int q = 0; q < 32; ++q) {
      const float* cp = C1m + (g + 4*q)*128 + kk*32;
      #pragma unroll
      for (int k2 = 0; k2 < 32; ++k2) acc[q] = fmaf(xr[k2], cp[k2], acc[q]);
    }
  }
  for (int m = 0; m < 64; ++m) {
    float uv = s_u[r*65 + m];
    #pragma unroll
    for (int q = 0; q < 32; ++q) acc[q] = fmaf(uv, D12[(g + 4*q)*64 + m], acc[q]);
  }
  #pragma unroll
  for (int q = 0; q < 32; ++q) s_bw[r*133 + (g + 4*q)] = acc[q];
  __syncthreads();

  // ---- recurrence: w[i] = tanh(base[i] + sum_{j<i} D11[i][j]*w[j]) ----
  {
    const int l = tid & 63;
    const int c = l & 3;           // 4 lanes per row
    const int rr = g*16 + (l >> 2);
    const int rb = rr*133;
    for (int i = 0; i < 128; ++i) {
      float p0 = 0.f;
      for (int j = c; j < i; j += 4)
        p0 = fmaf(D11m[i*128 + j], s_bw[rb + j], p0);
      p0 += __shfl_xor(p0, 1);
      p0 += __shfl_xor(p0, 2);
      float x = s_bw[rb + i] + p0;   // base, read before overwrite
      float v = fast_tanh(x);
      if (c == 0) s_bw[rb + i] = v;  // wave-synchronous, DS in-order
    }
  }
  __syncthreads();

  // ---- xi_dot = xi@A^T + w@B1^T + u@B2^T ; yi = xi@C2^T + w@D21^T + u@D22^T ----
  float ax[32], ay[16];
  #pragma unroll
  for (int q = 0; q < 32; ++q) ax[q] = 0.f;
  #pragma unroll
  for (int q = 0; q < 16; ++q) ay[q] = 0.f;

  for (int j = 0; j < 128; ++j) {
    float wv = s_bw[r*133 + j];
    #pragma unroll
    for (int q = 0; q < 32; ++q) ax[q] = fmaf(wv, B1m[(g + 4*q)*128 + j], ax[q]);
    #pragma unroll
    for (int q = 0; q < 16; ++q) ay[q] = fmaf(wv, D21[(g + 4*q)*128 + j], ay[q]);
  }
  for (int m = 0; m < 64; ++m) {
    float uv = s_u[r*65 + m];
    #pragma unroll
    for (int q = 0; q < 32; ++q) ax[q] = fmaf(uv, B2[(g + 4*q)*64 + m], ax[q]);
    #pragma unroll
    for (int q = 0; q < 16; ++q) ay[q] = fmaf(uv, D22[(g + 4*q)*64 + m], ay[q]);
  }
  for (int kk = 0; kk < 4; ++kk) {
    __syncthreads();
    for (int idx = tid; idx < 64*32; idx += 256) {
      int rr = idx >> 5, cc = idx & 31;
      s_xc[rr*33 + cc] = xi[(row0 + rr)*128 + kk*32 + cc];
    }
    __syncthreads();
    float xr[32];
    #pragma unroll
    for (int k2 = 0; k2 < 32; ++k2) xr[k2] = s_xc[r*33 + k2];
    #pragma unroll
    for (int q = 0; q < 32; ++q) {
      const float* ap = Am + (g + 4*q)*128 + kk*32;
      #pragma unroll
      for (int k2 = 0; k2 < 32; ++k2) ax[q] = fmaf(xr[k2], ap[k2], ax[q]);
    }
    #pragma unroll
    for (int q = 0; q < 16; ++q) {
      const float* cp = C2 + (g + 4*q)*128 + kk*32;
      #pragma unroll
      for (int k2 = 0; k2 < 32; ++k2) ay[q] = fmaf(xr[k2], cp[k2], ay[q]);
    }
  }

  #pragma unroll
  for (int q = 0; q < 32; ++q)
    out[(row0 + r)*128 + (g + 4*q)] = ax[q];
  const int yoff = BATCHc * 128;
  #pragma unroll
  for (int q = 0; q < 16; ++q)
    out[yoff + (row0 + r)*64 + (g + 4*q)] = ay[q];
}

extern "C" void kernel_launch(void* const* d_in, const int* in_sizes, int n_in,
                              void* d_out, int out_size, void* d_ws, size_t ws_size,
                              hipStream_t stream) {
  // inputs: 0:t 1:xi 2:u 3:Pstar 4:Chi 5:Y1 6:X 7:B2 8:D12 9:C2 10:D21 11:D22
  const float* xi    = (const float*)d_in[1];
  const float* u     = (const float*)d_in[2];
  const float* Pstar = (const float*)d_in[3];
  const float* Chi   = (const float*)d_in[4];
  const float* Y1    = (const float*)d_in[5];
  const float* X     = (const float*)d_in[6];
  const float* B2    = (const float*)d_in[7];
  const float* D12   = (const float*)d_in[8];
  const float* C2    = (const float*)d_in[9];
  const float* D21   = (const float*)d_in[10];
  const float* D22   = (const float*)d_in[11];
  float* out = (float*)d_out;
  float* ws  = (float*)d_ws;   // uses ~459 KB

  k1_params<<<320, 256, 0, stream>>>(Pstar, Chi, Y1, X, ws);
  k2_invert<<<1, 256, 0, stream>>>(ws);
  k3_solve<<<128, 256, 0, stream>>>(ws);
  k4_forward<<<(BATCHc/64), 256, 0, stream>>>(xi, u, ws, B2, D12, C2, D21, D22, out);
}

// Round 5
// 3001.687 us; speedup vs baseline: 1.5530x; 1.5509x over previous
//
#include <hip/hip_runtime.h>
#include <math.h>

// Problem constants
#define NXc 128
#define NQc 128
#define NUc 64
#define NYc 64
#define BATCHc 200000

// workspace layout (float offsets); total ~459 KB
#define WS_P    0
#define WS_Y    16384
#define WS_R    32768
#define WS_A    49152
#define WS_B1   65536
#define WS_C1   81920
#define WS_D11  98304   // NOTE: stored TRANSPOSED: D11T[j*128 + i] = D11[i][j]

__device__ __forceinline__ float fast_tanh(float x) {
  float e = __expf(2.0f * x);
  return 1.0f - 2.0f / (e + 1.0f);
}

// K1: compute P, Y, R, C1, D11^T into ws. 5*16384 elements, one thread each.
__global__ __launch_bounds__(256) void k1_params(
    const float* __restrict__ Pstar, const float* __restrict__ Chi,
    const float* __restrict__ Y1, const float* __restrict__ X,
    float* __restrict__ ws)
{
  int gid = blockIdx.x * 256 + threadIdx.x;
  int mat = gid >> 14;
  int idx = gid & 16383;
  int i = idx >> 7, j = idx & 127;
  if (mat == 0) {
    float s = 0.f;
    for (int k = 0; k < 128; ++k) s = fmaf(Pstar[i*128+k], Pstar[j*128+k], s);
    ws[WS_P + idx] = 0.5f*s + (i==j ? 0.01f : 0.f);
  } else if (mat == 1) {
    float s = 0.f;
    for (int k = 0; k < 256; ++k) s = fmaf(X[i*256+k], X[j*256+k], s);
    float h1 = s + (i==j ? 0.01f : 0.f);
    ws[WS_Y + idx] = -0.5f*(h1 + Y1[i*128+j] - Y1[j*128+i]);
  } else if (mat == 2) {
    float s = 0.f;
    for (int k = 0; k < 256; ++k) s = fmaf(X[i*256+k], X[(128+j)*256+k], s);
    ws[WS_R + idx] = -s - Chi[i*128+j];
  } else if (mat == 3) {
    float lam = 0.f;
    for (int k = 0; k < 256; ++k) { float v = X[(128+i)*256+k]; lam = fmaf(v, v, lam); }
    lam = 0.5f*(lam + 0.01f);
    ws[WS_C1 + idx] = Chi[j*128+i] / lam;
  } else {
    // D11[i][j] = (j<i) ? -H4[i][j]/lam[i] : 0 ; store TRANSPOSED at [j*128+i]
    float lam = 0.f, s = 0.f;
    for (int k = 0; k < 256; ++k) {
      float vi = X[(128+i)*256+k];
      lam = fmaf(vi, vi, lam);
      s = fmaf(vi, X[(128+j)*256+k], s);
    }
    lam = 0.5f*(lam + 0.01f);
    ws[WS_D11 + j*128 + i] = (j < i) ? (-s / lam) : 0.f;
  }
}

// K2: in-place Gauss-Jordan inversion of P (SPD, no pivoting), 1 block.
__global__ __launch_bounds__(256) void k2_invert(float* __restrict__ ws)
{
  __shared__ float Pls[128*130];
  __shared__ float fcol[128];
  const int t = threadIdx.x;
  for (int idx = t; idx < 16384; idx += 256) {
    int i = idx >> 7, j = idx & 127;
    Pls[i*130 + j] = ws[WS_P + idx];
  }
  __syncthreads();
  for (int k = 0; k < 128; ++k) {
    float pinv = 1.0f / Pls[k*130+k];
    if (t < 128) fcol[t] = Pls[t*130+k];
    __syncthreads();
    if (t < 128) {
      int j = t;
      if (j == k) Pls[k*130+j] = pinv;
      else        Pls[k*130+j] *= pinv;
    } else {
      int i = t - 128;
      if (i != k) Pls[i*130+k] = -fcol[i]*pinv;
    }
    __syncthreads();
    for (int idx = t; idx < 16384; idx += 256) {
      int i = idx >> 7, j = idx & 127;
      if (i != k && j != k) Pls[i*130+j] = fmaf(-fcol[i], Pls[k*130+j], Pls[i*130+j]);
    }
    __syncthreads();
  }
  for (int idx = t; idx < 16384; idx += 256) {
    int i = idx >> 7, j = idx & 127;
    ws[WS_P + idx] = Pls[i*130+j];
  }
}

// K3: A = Pinv@Y, B1 = Pinv@R. 128 blocks, 256 threads.
__global__ __launch_bounds__(256) void k3_solve(float* __restrict__ ws)
{
  const int i = blockIdx.x;
  const int t = threadIdx.x;
  const int j = t & 127;
  const int which = t >> 7;
  const float* Pinv = ws + WS_P;
  const float* Src  = ws + (which ? WS_R : WS_Y);
  float* Dst        = ws + (which ? WS_B1 : WS_A);
  float s = 0.f;
  for (int k = 0; k < 128; ++k) s = fmaf(Pinv[i*128+k], Src[k*128+j], s);
  Dst[i*128+j] = s;
}

// K4: fused forward, 64 batch rows per block, 256 threads = 4 waves.
__global__ __launch_bounds__(256) void k4_forward(
    const float* __restrict__ xi, const float* __restrict__ u,
    const float* __restrict__ ws,
    const float* __restrict__ B2, const float* __restrict__ D12,
    const float* __restrict__ C2, const float* __restrict__ D21,
    const float* __restrict__ D22,
    float* __restrict__ out)
{
  __shared__ float s_bw[64*133];      // base -> w -> xi_dot staging
  __shared__ float s_u[64*65];        // u tile -> yi staging
  __shared__ float s_xc[64*33];       // xi column-chunk
  __shared__ float s_d11[4*32*33];    // diagonal 32x32 tiles of D11

  const float* Am   = ws + WS_A;
  const float* B1m  = ws + WS_B1;
  const float* C1m  = ws + WS_C1;
  const float* D11T = ws + WS_D11;    // transposed: D11T[j*128+i] = D11[i][j]

  const int tid = threadIdx.x;
  const int r = tid & 63;
  const int g = __builtin_amdgcn_readfirstlane(tid >> 6);  // wave-uniform
  const int row0 = blockIdx.x * 64;

  // stage u tile (coalesced)
  for (int idx = tid; idx < 64*64; idx += 256) {
    int rr = idx >> 6, cc = idx & 63;
    s_u[rr*65 + cc] = u[(row0 + rr)*64 + cc];
  }
  // stage diagonal D11 tiles: s_d11[t][il][jl] = D11[32t+il][32t+jl] = D11T[(32t+jl)*128 + 32t+il]
  for (int e = tid; e < 4096; e += 256) {
    int t4 = e >> 10, rem = e & 1023, jl = rem >> 5, il = rem & 31;
    s_d11[t4*1056 + il*33 + jl] = D11T[(t4*32 + jl)*128 + (t4*32 + il)];
  }

  // ---- base = xi@C1^T + u@D12^T ----  (thread: row r, cols g+4q)
  float acc[32];
  #pragma unroll
  for (int q = 0; q < 32; ++q) acc[q] = 0.f;

  for (int kk = 0; kk < 4; ++kk) {
    __syncthreads();
    for (int idx = tid; idx < 64*32; idx += 256) {
      int rr = idx >> 5, cc = idx & 31;
      s_xc[rr*33 + cc] = xi[(row0 + rr)*128 + kk*32 + cc];
    }
    __syncthreads();
    float xr[32];
    #pragma unroll
    for (int k2 = 0; k2 < 32; ++k2) xr[k2] = s_xc[r*33 + k2];
    #pragma unroll
    for (int q = 0; q < 32; ++q) {
      const float4* cp = (const float4*)(C1m + (g + 4*q)*128 + kk*32);
      #pragma unroll
      for (int k4 = 0; k4 < 8; ++k4) {
        float4 cv = cp[k4];
        acc[q] = fmaf(xr[4*k4+0], cv.x, acc[q]);
        acc[q] = fmaf(xr[4*k4+1], cv.y, acc[q]);
        acc[q] = fmaf(xr[4*k4+2], cv.z, acc[q]);
        acc[q] = fmaf(xr[4*k4+3], cv.w, acc[q]);
      }
    }
  }
  for (int m0 = 0; m0 < 16; ++m0) {
    float u0 = s_u[r*65 + 4*m0 + 0];
    float u1 = s_u[r*65 + 4*m0 + 1];
    float u2 = s_u[r*65 + 4*m0 + 2];
    float u3 = s_u[r*65 + 4*m0 + 3];
    #pragma unroll
    for (int q = 0; q < 32; ++q) {
      float4 dv = *(const float4*)(D12 + (g + 4*q)*64 + 4*m0);
      acc[q] = fmaf(u0, dv.x, acc[q]);
      acc[q] = fmaf(u1, dv.y, acc[q]);
      acc[q] = fmaf(u2, dv.z, acc[q]);
      acc[q] = fmaf(u3, dv.w, acc[q]);
    }
  }
  #pragma unroll
  for (int q = 0; q < 32; ++q) s_bw[r*133 + (g + 4*q)] = acc[q];
  __syncthreads();

  // ---- recurrence, blocked forward substitution, tile T=32 ----
  {
    const int c  = tid & 3;                 // 4 lanes per row
    const int rr = g*16 + ((tid & 63) >> 2);
    const int rb = rr*133;
    for (int t = 0; t < 4; ++t) {
      const int i0 = t*32;
      // inter-tile GEMM: base[:, i0..i0+31] += w[:, 0..i0) @ D11[i0+i, j]
      // thread: row r, cols i = g*8 + q (q=0..7)
      if (t > 0) {
        float pacc[8];
        #pragma unroll
        for (int q = 0; q < 8; ++q) pacc[q] = 0.f;
        for (int j = 0; j < i0; ++j) {
          float wv = s_bw[r*133 + j];
          const float* dp = D11T + j*128 + i0 + g*8;
          float4 d0 = *(const float4*)(dp);
          float4 d1 = *(const float4*)(dp + 4);
          pacc[0] = fmaf(wv, d0.x, pacc[0]);
          pacc[1] = fmaf(wv, d0.y, pacc[1]);
          pacc[2] = fmaf(wv, d0.z, pacc[2]);
          pacc[3] = fmaf(wv, d0.w, pacc[3]);
          pacc[4] = fmaf(wv, d1.x, pacc[4]);
          pacc[5] = fmaf(wv, d1.y, pacc[5]);
          pacc[6] = fmaf(wv, d1.z, pacc[6]);
          pacc[7] = fmaf(wv, d1.w, pacc[7]);
        }
        #pragma unroll
        for (int q = 0; q < 8; ++q)
          s_bw[r*133 + i0 + g*8 + q] += pacc[q];
      }
      __syncthreads();
      // sequential 32 steps, w replicated in registers by residue class:
      // wq[k] (lane c) holds w[i0 + 4k + c]
      const float* dt = s_d11 + t*1056;
      float wq[8];
      #pragma unroll
      for (int k = 0; k < 8; ++k) wq[k] = 0.f;
      #pragma unroll
      for (int il = 0; il < 32; ++il) {
        float p0 = 0.f;
        const int nf = il >> 2;
        #pragma unroll
        for (int k = 0; k < nf; ++k)
          p0 = fmaf(dt[il*33 + 4*k + c], wq[k], p0);
        if ((il & 3) && c < (il & 3))
          p0 = fmaf(dt[il*33 + 4*nf + c], wq[nf], p0);
        p0 += __shfl_xor(p0, 1);
        p0 += __shfl_xor(p0, 2);
        float v = fast_tanh(s_bw[rb + i0 + il] + p0);
        if (c == (il & 3)) wq[nf] = v;
        if (c == 0) s_bw[rb + i0 + il] = v;   // wave-synchronous, DS in-order
      }
      __syncthreads();
    }
  }

  // ---- xi_dot = xi@A^T + w@B1^T + u@B2^T ; yi = xi@C2^T + w@D21^T + u@D22^T ----
  float ax[32], ay[16];
  #pragma unroll
  for (int q = 0; q < 32; ++q) ax[q] = 0.f;
  #pragma unroll
  for (int q = 0; q < 16; ++q) ay[q] = 0.f;

  for (int j0 = 0; j0 < 32; ++j0) {
    float w0 = s_bw[r*133 + 4*j0 + 0];
    float w1 = s_bw[r*133 + 4*j0 + 1];
    float w2 = s_bw[r*133 + 4*j0 + 2];
    float w3 = s_bw[r*133 + 4*j0 + 3];
    #pragma unroll
    for (int q = 0; q < 32; ++q) {
      float4 b = *(const float4*)(B1m + (g + 4*q)*128 + 4*j0);
      ax[q] = fmaf(w0, b.x, ax[q]);
      ax[q] = fmaf(w1, b.y, ax[q]);
      ax[q] = fmaf(w2, b.z, ax[q]);
      ax[q] = fmaf(w3, b.w, ax[q]);
    }
    #pragma unroll
    for (int q = 0; q < 16; ++q) {
      float4 d = *(const float4*)(D21 + (g + 4*q)*128 + 4*j0);
      ay[q] = fmaf(w0, d.x, ay[q]);
      ay[q] = fmaf(w1, d.y, ay[q]);
      ay[q] = fmaf(w2, d.z, ay[q]);
      ay[q] = fmaf(w3, d.w, ay[q]);
    }
  }
  for (int m0 = 0; m0 < 16; ++m0) {
    float u0 = s_u[r*65 + 4*m0 + 0];
    float u1 = s_u[r*65 + 4*m0 + 1];
    float u2 = s_u[r*65 + 4*m0 + 2];
    float u3 = s_u[r*65 + 4*m0 + 3];
    #pragma unroll
    for (int q = 0; q < 32; ++q) {
      float4 b = *(const float4*)(B2 + (g + 4*q)*64 + 4*m0);
      ax[q] = fmaf(u0, b.x, ax[q]);
      ax[q] = fmaf(u1, b.y, ax[q]);
      ax[q] = fmaf(u2, b.z, ax[q]);
      ax[q] = fmaf(u3, b.w, ax[q]);
    }
    #pragma unroll
    for (int q = 0; q < 16; ++q) {
      float4 d = *(const float4*)(D22 + (g + 4*q)*64 + 4*m0);
      ay[q] = fmaf(u0, d.x, ay[q]);
      ay[q] = fmaf(u1, d.y, ay[q]);
      ay[q] = fmaf(u2, d.z, ay[q]);
      ay[q] = fmaf(u3, d.w, ay[q]);
    }
  }
  for (int kk = 0; kk < 4; ++kk) {
    __syncthreads();
    for (int idx = tid; idx < 64*32; idx += 256) {
      int rr = idx >> 5, cc = idx & 31;
      s_xc[rr*33 + cc] = xi[(row0 + rr)*128 + kk*32 + cc];
    }
    __syncthreads();
    float xr[32];
    #pragma unroll
    for (int k2 = 0; k2 < 32; ++k2) xr[k2] = s_xc[r*33 + k2];
    #pragma unroll
    for (int q = 0; q < 32; ++q) {
      const float4* ap = (const float4*)(Am + (g + 4*q)*128 + kk*32);
      #pragma unroll
      for (int k4 = 0; k4 < 8; ++k4) {
        float4 av = ap[k4];
        ax[q] = fmaf(xr[4*k4+0], av.x, ax[q]);
        ax[q] = fmaf(xr[4*k4+1], av.y, ax[q]);
        ax[q] = fmaf(xr[4*k4+2], av.z, ax[q]);
        ax[q] = fmaf(xr[4*k4+3], av.w, ax[q]);
      }
    }
    #pragma unroll
    for (int q = 0; q < 16; ++q) {
      const float4* cp = (const float4*)(C2 + (g + 4*q)*128 + kk*32);
      #pragma unroll
      for (int k4 = 0; k4 < 8; ++k4) {
        float4 cv = cp[k4];
        ay[q] = fmaf(xr[4*k4+0], cv.x, ay[q]);
        ay[q] = fmaf(xr[4*k4+1], cv.y, ay[q]);
        ay[q] = fmaf(xr[4*k4+2], cv.z, ay[q]);
        ay[q] = fmaf(xr[4*k4+3], cv.w, ay[q]);
      }
    }
  }

  // ---- transpose results through LDS, then coalesced float4 stores ----
  __syncthreads();   // all reads of s_bw (w) and s_u (u) are done
  #pragma unroll
  for (int q = 0; q < 32; ++q) s_bw[r*133 + (g + 4*q)] = ax[q];
  #pragma unroll
  for (int q = 0; q < 16; ++q) s_u[r*65 + (g + 4*q)] = ay[q];
  __syncthreads();

  #pragma unroll
  for (int s = 0; s < 8; ++s) {
    int f = tid + 256*s;
    int rr = f >> 5, c4 = f & 31;
    float4 v;
    v.x = s_bw[rr*133 + 4*c4 + 0];
    v.y = s_bw[rr*133 + 4*c4 + 1];
    v.z = s_bw[rr*133 + 4*c4 + 2];
    v.w = s_bw[rr*133 + 4*c4 + 3];
    *(float4*)(out + (size_t)(row0 + rr)*128 + 4*c4) = v;
  }
  const size_t yoff = (size_t)BATCHc * 128;
  #pragma unroll
  for (int s = 0; s < 4; ++s) {
    int f = tid + 256*s;
    int rr = f >> 4, c4 = f & 15;
    float4 v;
    v.x = s_u[rr*65 + 4*c4 + 0];
    v.y = s_u[rr*65 + 4*c4 + 1];
    v.z = s_u[rr*65 + 4*c4 + 2];
    v.w = s_u[rr*65 + 4*c4 + 3];
    *(float4*)(out + yoff + (size_t)(row0 + rr)*64 + 4*c4) = v;
  }
}

extern "C" void kernel_launch(void* const* d_in, const int* in_sizes, int n_in,
                              void* d_out, int out_size, void* d_ws, size_t ws_size,
                              hipStream_t stream) {
  // inputs: 0:t 1:xi 2:u 3:Pstar 4:Chi 5:Y1 6:X 7:B2 8:D12 9:C2 10:D21 11:D22
  const float* xi    = (const float*)d_in[1];
  const float* u     = (const float*)d_in[2];
  const float* Pstar = (const float*)d_in[3];
  const float* Chi   = (const float*)d_in[4];
  const float* Y1    = (const float*)d_in[5];
  const float* X     = (const float*)d_in[6];
  const float* B2    = (const float*)d_in[7];
  const float* D12   = (const float*)d_in[8];
  const float* C2    = (const float*)d_in[9];
  const float* D21   = (const float*)d_in[10];
  const float* D22   = (const float*)d_in[11];
  float* out = (float*)d_out;
  float* ws  = (float*)d_ws;

  k1_params<<<320, 256, 0, stream>>>(Pstar, Chi, Y1, X, ws);
  k2_invert<<<1, 256, 0, stream>>>(ws);
  k3_solve<<<128, 256, 0, stream>>>(ws);
  k4_forward<<<(BATCHc/64), 256, 0, stream>>>(xi, u, ws, B2, D12, C2, D21, D22, out);
}

// Round 6
// 696.048 us; speedup vs baseline: 6.6973x; 4.3125x over previous
//
#include <hip/hip_runtime.h>
#include <math.h>

// Problem constants
#define NXc 128
#define NQc 128
#define NUc 64
#define NYc 64
#define BATCHc 200000

// ---- workspace layout ----
// float offsets:
#define WS_P    0        // P -> Pinv (dead after k3; overlaid by frags in kcvt)
#define WS_Y    16384    // (dead after k3; overlaid by frags)
#define WS_R    32768    // (dead after k3; overlaid by frags)
#define WS_A    49152
#define WS_B1   65536
#define WS_D11  81920    // D11T fp32: D11T[j*128+i] = D11[i][j]
#define WS_LAM  98304    // 128 floats
// bf16 frag arrays, ushort offsets from (ushort*)ws (bytes 0..172032, overlays P/Y/R after k3):
#define FB_A    0
#define FB_B1   16384
#define FB_C1   32768
#define FB_D12  49152
#define FB_B2   57344
#define FB_C2   65536
#define FB_D21  73728
#define FB_D22  81920

typedef __attribute__((ext_vector_type(8))) short s16x8;
typedef __attribute__((ext_vector_type(4))) float f32x4;
#define MFMA __builtin_amdgcn_mfma_f32_16x16x32_bf16

__device__ __forceinline__ float fast_tanh(float x) {
  float e = __expf(2.0f * x);
  return 1.0f - 2.0f / (e + 1.0f);
}

__device__ __forceinline__ ushort f2bf(float f) {
  unsigned int u = __builtin_bit_cast(unsigned int, f);
  u = (u + 0x7FFFu + ((u >> 16) & 1u)) >> 16;
  return (ushort)u;
}

// frag index for matrix (N x K) row-major, element (n,k):
// lane = (n&15) + 16*((k&31)>>3), e = k&7, frag = (n>>4)*(K/32) + (k>>5)
__device__ __forceinline__ int frag_idx(int n, int k, int KS) {
  int lane = (n & 15) + (((k >> 3) & 3) << 4);
  return ((((n >> 4) * KS + (k >> 5)) << 6) + lane) * 8 + (k & 7);
}

// K1: P, Y, R, lam, D11T into ws.
__global__ __launch_bounds__(256) void k1_params(
    const float* __restrict__ Pstar, const float* __restrict__ Chi,
    const float* __restrict__ Y1, const float* __restrict__ X,
    float* __restrict__ ws)
{
  int gid = blockIdx.x * 256 + threadIdx.x;
  int mat = gid >> 14;
  int idx = gid & 16383;
  int i = idx >> 7, j = idx & 127;
  if (mat == 0) {
    float s = 0.f;
    for (int k = 0; k < 128; ++k) s = fmaf(Pstar[i*128+k], Pstar[j*128+k], s);
    ws[WS_P + idx] = 0.5f*s + (i==j ? 0.01f : 0.f);
  } else if (mat == 1) {
    float s = 0.f;
    for (int k = 0; k < 256; ++k) s = fmaf(X[i*256+k], X[j*256+k], s);
    float h1 = s + (i==j ? 0.01f : 0.f);
    ws[WS_Y + idx] = -0.5f*(h1 + Y1[i*128+j] - Y1[j*128+i]);
  } else if (mat == 2) {
    float s = 0.f;
    for (int k = 0; k < 256; ++k) s = fmaf(X[i*256+k], X[(128+j)*256+k], s);
    ws[WS_R + idx] = -s - Chi[i*128+j];
  } else if (mat == 3) {
    if (j == 0) {
      float lam = 0.f;
      for (int k = 0; k < 256; ++k) { float v = X[(128+i)*256+k]; lam = fmaf(v, v, lam); }
      ws[WS_LAM + i] = 0.5f*(lam + 0.01f);
    }
  } else {
    float lam = 0.f, s = 0.f;
    for (int k = 0; k < 256; ++k) {
      float vi = X[(128+i)*256+k];
      lam = fmaf(vi, vi, lam);
      s = fmaf(vi, X[(128+j)*256+k], s);
    }
    lam = 0.5f*(lam + 0.01f);
    ws[WS_D11 + j*128 + i] = (j < i) ? (-s / lam) : 0.f;
  }
}

// K2: Gauss-Jordan inversion of P (SPD), 1 block x 1024 threads.
__global__ __launch_bounds__(1024) void k2_invert(float* __restrict__ ws)
{
  __shared__ float Pls[128*130];
  __shared__ float fcol[128];
  const int t = threadIdx.x;
  for (int idx = t; idx < 16384; idx += 1024) {
    int i = idx >> 7, j = idx & 127;
    Pls[i*130 + j] = ws[WS_P + idx];
  }
  __syncthreads();
  for (int k = 0; k < 128; ++k) {
    float pinv = 1.0f / Pls[k*130+k];
    if (t < 128) fcol[t] = Pls[t*130+k];
    __syncthreads();
    if (t < 128) {
      int j = t;
      if (j == k) Pls[k*130+j] = pinv;
      else        Pls[k*130+j] *= pinv;
    } else if (t < 256) {
      int i = t - 128;
      if (i != k) Pls[i*130+k] = -fcol[i]*pinv;
    }
    __syncthreads();
    for (int idx = t; idx < 16384; idx += 1024) {
      int i = idx >> 7, j = idx & 127;
      if (i != k && j != k) Pls[i*130+j] = fmaf(-fcol[i], Pls[k*130+j], Pls[i*130+j]);
    }
    __syncthreads();
  }
  for (int idx = t; idx < 16384; idx += 1024) {
    int i = idx >> 7, j = idx & 127;
    ws[WS_P + idx] = Pls[i*130+j];
  }
}

// K3: A = Pinv@Y, B1 = Pinv@R.
__global__ __launch_bounds__(256) void k3_solve(float* __restrict__ ws)
{
  const int i = blockIdx.x;
  const int t = threadIdx.x;
  const int j = t & 127;
  const int which = t >> 7;
  const float* Pinv = ws + WS_P;
  const float* Src  = ws + (which ? WS_R : WS_Y);
  float* Dst        = ws + (which ? WS_B1 : WS_A);
  float s = 0.f;
  for (int k = 0; k < 128; ++k) s = fmaf(Pinv[i*128+k], Src[k*128+j], s);
  Dst[i*128+j] = s;
}

// KCVT: pack all GEMM B-operand matrices into bf16 frag-ordered arrays (overlays P/Y/R).
__global__ __launch_bounds__(256) void kcvt(
    const float* __restrict__ Chi, const float* __restrict__ D12,
    const float* __restrict__ B2, const float* __restrict__ C2,
    const float* __restrict__ D21, const float* __restrict__ D22,
    float* __restrict__ ws)
{
  int gid = blockIdx.x * 256 + threadIdx.x;
  ushort* dstb = (ushort*)ws;
  float val; int n, k, KS, dst;
  if (gid < 16384)      { int l = gid;        n=l>>7; k=l&127; KS=4; val = ws[WS_A + l];  dst = FB_A; }
  else if (gid < 32768) { int l = gid-16384;  n=l>>7; k=l&127; KS=4; val = ws[WS_B1 + l]; dst = FB_B1; }
  else if (gid < 49152) { int l = gid-32768;  n=l>>7; k=l&127; KS=4;
                          val = Chi[k*128+n] / ws[WS_LAM + n];        dst = FB_C1; }
  else if (gid < 57344) { int l = gid-49152;  n=l>>6; k=l&63;  KS=2; val = D12[l]; dst = FB_D12; }
  else if (gid < 65536) { int l = gid-57344;  n=l>>6; k=l&63;  KS=2; val = B2[l];  dst = FB_B2; }
  else if (gid < 73728) { int l = gid-65536;  n=l>>7; k=l&127; KS=4; val = C2[l];  dst = FB_C2; }
  else if (gid < 81920) { int l = gid-73728;  n=l>>7; k=l&127; KS=4; val = D21[l]; dst = FB_D21; }
  else                  { int l = gid-81920;  n=l>>6; k=l&63;  KS=2; val = D22[l]; dst = FB_D22; }
  dstb[dst + frag_idx(n, k, KS)] = f2bf(val);
}

// ---- K4 LDS layout (bytes) ----
#define LDS_XI   0        // 16384: bf16 A-frags of xi tile [mt*4+ks][lane][8]
#define LDS_U    16384    // 8192 : bf16 A-frags of u tile  [mt*2+ks][lane][8]
#define LDS_WD   24576    // 16896: union { s_d11 diag f32 (4*32*33*4) ; s_w bf16 frags (16384) }
#define LDS_BW   41472    // 33024: s_bw f32 [64][129]
#define LDS_TOT  74496

// K4: fused forward, 64 batch rows/block, 256 threads = 4 waves (wave g owns m-tile g).
__global__ __launch_bounds__(256) void k4_forward(
    const float* __restrict__ xi, const float* __restrict__ u,
    const float* __restrict__ ws,
    float* __restrict__ out)
{
  __shared__ __align__(16) char smem[LDS_TOT];
  float* s_bw  = (float*)(smem + LDS_BW);
  float* s_d11 = (float*)(smem + LDS_WD);

  const float* D11T = ws + WS_D11;
  const ushort* wsb = (const ushort*)ws;

  const int tid  = threadIdx.x;
  const int lane = tid & 63;
  const int g    = __builtin_amdgcn_readfirstlane(tid >> 6);
  const int row0 = blockIdx.x * 64;

  // ---- stage xi tile as bf16 A-frags (coalesced float4 reads) ----
  #pragma unroll
  for (int it = 0; it < 8; ++it) {
    int idx = it*256 + tid;
    int rr = idx >> 5, ck = idx & 31;              // 4-float chunk ck of row rr
    float4 v = *(const float4*)(xi + (size_t)(row0 + rr)*128 + ck*4);
    ushort4 o; o.x = f2bf(v.x); o.y = f2bf(v.y); o.z = f2bf(v.z); o.w = f2bf(v.w);
    int blk  = ((rr >> 4) << 2) + (ck >> 3);
    int lns  = (rr & 15) + (((ck & 7) >> 1) << 4);
    *(ushort4*)(smem + LDS_XI + blk*1024 + lns*16 + (ck & 1)*8) = o;
  }
  // ---- stage u tile ----
  #pragma unroll
  for (int it = 0; it < 4; ++it) {
    int idx = it*256 + tid;
    int rr = idx >> 4, ck = idx & 15;
    float4 v = *(const float4*)(u + (size_t)(row0 + rr)*64 + ck*4);
    ushort4 o; o.x = f2bf(v.x); o.y = f2bf(v.y); o.z = f2bf(v.z); o.w = f2bf(v.w);
    int blk  = ((rr >> 4) << 1) + (ck >> 3);
    int lns  = (rr & 15) + (((ck & 7) >> 1) << 4);
    *(ushort4*)(smem + LDS_U + blk*1024 + lns*16 + (ck & 1)*8) = o;
  }
  // ---- stage diagonal D11 tiles (fp32) ----
  for (int e = tid; e < 4096; e += 256) {
    int t4 = e >> 10, rem = e & 1023, jl = rem >> 5, il = rem & 31;
    s_d11[t4*1056 + il*33 + jl] = D11T[(t4*32 + jl)*128 + (t4*32 + il)];
  }
  __syncthreads();

  const int rl = (lane >> 4) * 4;   // C/D row base within m-tile
  const int cl = lane & 15;         // C/D col within n-tile

  // ---- base = xi@C1^T + u@D12^T  (MFMA) ----
  {
    f32x4 accb[8];
    #pragma unroll
    for (int nt = 0; nt < 8; ++nt) accb[nt] = (f32x4){0.f,0.f,0.f,0.f};
    #pragma unroll
    for (int ks = 0; ks < 4; ++ks) {
      s16x8 af = *(const s16x8*)(smem + LDS_XI + (((g*4+ks)<<6) + lane)*16);
      #pragma unroll
      for (int nt = 0; nt < 8; ++nt) {
        s16x8 bf = *(const s16x8*)(wsb + FB_C1 + ((((nt*4+ks)<<6) + lane)<<3));
        accb[nt] = MFMA(af, bf, accb[nt], 0, 0, 0);
      }
    }
    #pragma unroll
    for (int ks = 0; ks < 2; ++ks) {
      s16x8 af = *(const s16x8*)(smem + LDS_U + (((g*2+ks)<<6) + lane)*16);
      #pragma unroll
      for (int nt = 0; nt < 8; ++nt) {
        s16x8 bf = *(const s16x8*)(wsb + FB_D12 + ((((nt*2+ks)<<6) + lane)<<3));
        accb[nt] = MFMA(af, bf, accb[nt], 0, 0, 0);
      }
    }
    #pragma unroll
    for (int nt = 0; nt < 8; ++nt)
      #pragma unroll
      for (int r = 0; r < 4; ++r)
        s_bw[(g*16 + rl + r)*129 + nt*16 + cl] = accb[nt][r];
  }
  __syncthreads();

  // ---- recurrence: blocked forward substitution, tile 32 (fp32) ----
  {
    const int r  = tid & 63;
    const int c  = tid & 3;
    const int rr = g*16 + ((tid & 63) >> 2);
    const int rb = rr*129;
    #pragma unroll
    for (int t = 0; t < 4; ++t) {
      const int i0 = t*32;
      if (t > 0) {
        float pacc[8];
        #pragma unroll
        for (int q = 0; q < 8; ++q) pacc[q] = 0.f;
        for (int j = 0; j < i0; ++j) {
          float wv = s_bw[r*129 + j];
          const float* dp = D11T + j*128 + i0 + g*8;
          float4 d0 = *(const float4*)(dp);
          float4 d1 = *(const float4*)(dp + 4);
          pacc[0] = fmaf(wv, d0.x, pacc[0]);
          pacc[1] = fmaf(wv, d0.y, pacc[1]);
          pacc[2] = fmaf(wv, d0.z, pacc[2]);
          pacc[3] = fmaf(wv, d0.w, pacc[3]);
          pacc[4] = fmaf(wv, d1.x, pacc[4]);
          pacc[5] = fmaf(wv, d1.y, pacc[5]);
          pacc[6] = fmaf(wv, d1.z, pacc[6]);
          pacc[7] = fmaf(wv, d1.w, pacc[7]);
        }
        #pragma unroll
        for (int q = 0; q < 8; ++q)
          s_bw[r*129 + i0 + g*8 + q] += pacc[q];
      }
      __syncthreads();
      const float* dt = s_d11 + t*1056;
      float wq[8];
      #pragma unroll
      for (int k = 0; k < 8; ++k) wq[k] = 0.f;
      #pragma unroll
      for (int il = 0; il < 32; ++il) {
        float p0 = 0.f;
        const int nf = il >> 2;
        #pragma unroll
        for (int k = 0; k < nf; ++k)
          p0 = fmaf(dt[il*33 + 4*k + c], wq[k], p0);
        if ((il & 3) && c < (il & 3))
          p0 = fmaf(dt[il*33 + 4*nf + c], wq[nf], p0);
        p0 += __shfl_xor(p0, 1);
        p0 += __shfl_xor(p0, 2);
        float v = fast_tanh(s_bw[rb + i0 + il] + p0);
        if (c == (il & 3)) wq[nf] = v;
        if (c == 0) s_bw[rb + i0 + il] = v;   // wave-synchronous
      }
      __syncthreads();
    }
  }

  // ---- convert w -> bf16 A-frags (into s_w region, s_d11 now dead) ----
  #pragma unroll
  for (int it = 0; it < 8; ++it) {
    int idx = it*256 + tid;
    int rr = idx >> 5, ck = idx & 31;
    float v0 = s_bw[rr*129 + ck*4 + 0];
    float v1 = s_bw[rr*129 + ck*4 + 1];
    float v2 = s_bw[rr*129 + ck*4 + 2];
    float v3 = s_bw[rr*129 + ck*4 + 3];
    ushort4 o; o.x = f2bf(v0); o.y = f2bf(v1); o.z = f2bf(v2); o.w = f2bf(v3);
    int blk  = ((rr >> 4) << 2) + (ck >> 3);
    int lns  = (rr & 15) + (((ck & 7) >> 1) << 4);
    *(ushort4*)(smem + LDS_WD + blk*1024 + lns*16 + (ck & 1)*8) = o;
  }
  __syncthreads();

  // ---- xi_dot = xi@A^T + w@B1^T + u@B2^T ; yi = xi@C2^T + w@D21^T + u@D22^T (MFMA) ----
  f32x4 ax[8], ay[4];
  #pragma unroll
  for (int nt = 0; nt < 8; ++nt) ax[nt] = (f32x4){0.f,0.f,0.f,0.f};
  #pragma unroll
  for (int nt = 0; nt < 4; ++nt) ay[nt] = (f32x4){0.f,0.f,0.f,0.f};

  #pragma unroll
  for (int ks = 0; ks < 4; ++ks) {
    s16x8 af = *(const s16x8*)(smem + LDS_XI + (((g*4+ks)<<6) + lane)*16);
    #pragma unroll
    for (int nt = 0; nt < 8; ++nt) {
      s16x8 bf = *(const s16x8*)(wsb + FB_A + ((((nt*4+ks)<<6) + lane)<<3));
      ax[nt] = MFMA(af, bf, ax[nt], 0, 0, 0);
    }
    #pragma unroll
    for (int nt = 0; nt < 4; ++nt) {
      s16x8 bf = *(const s16x8*)(wsb + FB_C2 + ((((nt*4+ks)<<6) + lane)<<3));
      ay[nt] = MFMA(af, bf, ay[nt], 0, 0, 0);
    }
  }
  #pragma unroll
  for (int ks = 0; ks < 4; ++ks) {
    s16x8 af = *(const s16x8*)(smem + LDS_WD + (((g*4+ks)<<6) + lane)*16);
    #pragma unroll
    for (int nt = 0; nt < 8; ++nt) {
      s16x8 bf = *(const s16x8*)(wsb + FB_B1 + ((((nt*4+ks)<<6) + lane)<<3));
      ax[nt] = MFMA(af, bf, ax[nt], 0, 0, 0);
    }
    #pragma unroll
    for (int nt = 0; nt < 4; ++nt) {
      s16x8 bf = *(const s16x8*)(wsb + FB_D21 + ((((nt*4+ks)<<6) + lane)<<3));
      ay[nt] = MFMA(af, bf, ay[nt], 0, 0, 0);
    }
  }
  #pragma unroll
  for (int ks = 0; ks < 2; ++ks) {
    s16x8 af = *(const s16x8*)(smem + LDS_U + (((g*2+ks)<<6) + lane)*16);
    #pragma unroll
    for (int nt = 0; nt < 8; ++nt) {
      s16x8 bf = *(const s16x8*)(wsb + FB_B2 + ((((nt*2+ks)<<6) + lane)<<3));
      ax[nt] = MFMA(af, bf, ax[nt], 0, 0, 0);
    }
    #pragma unroll
    for (int nt = 0; nt < 4; ++nt) {
      s16x8 bf = *(const s16x8*)(wsb + FB_D22 + ((((nt*2+ks)<<6) + lane)<<3));
      ay[nt] = MFMA(af, bf, ay[nt], 0, 0, 0);
    }
  }

  // ---- stores (C/D layout: row = 16g + rl + r, col = nt*16 + cl) ----
  #pragma unroll
  for (int nt = 0; nt < 8; ++nt)
    #pragma unroll
    for (int r = 0; r < 4; ++r)
      out[(size_t)(row0 + g*16 + rl + r)*128 + nt*16 + cl] = ax[nt][r];
  const size_t yoff = (size_t)BATCHc * 128;
  #pragma unroll
  for (int nt = 0; nt < 4; ++nt)
    #pragma unroll
    for (int r = 0; r < 4; ++r)
      out[yoff + (size_t)(row0 + g*16 + rl + r)*64 + nt*16 + cl] = ay[nt][r];
}

extern "C" void kernel_launch(void* const* d_in, const int* in_sizes, int n_in,
                              void* d_out, int out_size, void* d_ws, size_t ws_size,
                              hipStream_t stream) {
  // inputs: 0:t 1:xi 2:u 3:Pstar 4:Chi 5:Y1 6:X 7:B2 8:D12 9:C2 10:D21 11:D22
  const float* xi    = (const float*)d_in[1];
  const float* u     = (const float*)d_in[2];
  const float* Pstar = (const float*)d_in[3];
  const float* Chi   = (const float*)d_in[4];
  const float* Y1    = (const float*)d_in[5];
  const float* X     = (const float*)d_in[6];
  const float* B2    = (const float*)d_in[7];
  const float* D12   = (const float*)d_in[8];
  const float* C2    = (const float*)d_in[9];
  const float* D21   = (const float*)d_in[10];
  const float* D22   = (const float*)d_in[11];
  float* out = (float*)d_out;
  float* ws  = (float*)d_ws;   // uses ~394 KB

  k1_params<<<320, 256, 0, stream>>>(Pstar, Chi, Y1, X, ws);
  k2_invert<<<1, 1024, 0, stream>>>(ws);
  k3_solve<<<128, 256, 0, stream>>>(ws);
  kcvt<<<336, 256, 0, stream>>>(Chi, D12, B2, C2, D21, D22, ws);
  k4_forward<<<(BATCHc/64), 256, 0, stream>>>(xi, u, ws, out);
}

// Round 7
// 488.306 us; speedup vs baseline: 9.5466x; 1.4254x over previous
//
#include <hip/hip_runtime.h>
#include <math.h>

// Problem constants
#define BATCHc 200000

// ---- workspace layout ----
// float offsets:
#define WS_P    0        // dead after k3; overlaid by frags in kcvt
#define WS_Y    16384
#define WS_R    32768
#define WS_A    49152
#define WS_B1   65536
#define WS_D11  81920    // D11T fp32: D11T[j*128+i] = D11[i][j]
#define WS_LAM  98304    // 128 floats
// bf16 frag arrays, ushort offsets from (ushort*)ws:
#define FB_A    0        // overlay P/Y/R region (bytes < 172032 < 196608)
#define FB_B1   16384
#define FB_C1   32768
#define FB_D12  49152
#define FB_B2   57344
#define FB_C2   65536
#define FB_D21  73728
#define FB_D22  81920    // ends 86016
#define FB_D11  197120   // float off 98560.. (16384 ushorts, after WS_LAM)
#define FB_DIAG 213504   // 4096 ushorts packed [4][32][32]; ends byte 435200

typedef __attribute__((ext_vector_type(8))) short s16x8;
typedef __attribute__((ext_vector_type(8))) unsigned short u16x8;
typedef __attribute__((ext_vector_type(4))) float f32x4;
#define MFMA __builtin_amdgcn_mfma_f32_16x16x32_bf16

__device__ __forceinline__ float fast_tanh(float x) {
  float e = __expf(2.0f * x);
  return 1.0f - 2.0f / (e + 1.0f);
}
__device__ __forceinline__ ushort f2bf(float f) {
  unsigned int u = __builtin_bit_cast(unsigned int, f);
  u = (u + 0x7FFFu + ((u >> 16) & 1u)) >> 16;
  return (ushort)u;
}
__device__ __forceinline__ float bf2f(ushort h) {
  return __builtin_bit_cast(float, (unsigned int)h << 16);
}
// 4-lane (quad) butterfly reduce via DPP quad_perm — VALU-latency, no LDS
__device__ __forceinline__ float qreduce(float x) {
  int a = __builtin_amdgcn_mov_dpp(__builtin_bit_cast(int, x), 0xB1, 0xF, 0xF, true);
  x += __builtin_bit_cast(float, a);
  int b = __builtin_amdgcn_mov_dpp(__builtin_bit_cast(int, x), 0x4E, 0xF, 0xF, true);
  x += __builtin_bit_cast(float, b);
  return x;
}

// frag index for matrix (N x K) row-major, element (n,k):
__device__ __forceinline__ int frag_idx(int n, int k, int KS) {
  int lane = (n & 15) + (((k >> 3) & 3) << 4);
  return ((((n >> 4) * KS + (k >> 5)) << 6) + lane) * 8 + (k & 7);
}

// K1: P, Y, R, lam, D11T into ws.
__global__ __launch_bounds__(256) void k1_params(
    const float* __restrict__ Pstar, const float* __restrict__ Chi,
    const float* __restrict__ Y1, const float* __restrict__ X,
    float* __restrict__ ws)
{
  int gid = blockIdx.x * 256 + threadIdx.x;
  int mat = gid >> 14;
  int idx = gid & 16383;
  int i = idx >> 7, j = idx & 127;
  if (mat == 0) {
    float s = 0.f;
    for (int k = 0; k < 128; ++k) s = fmaf(Pstar[i*128+k], Pstar[j*128+k], s);
    ws[WS_P + idx] = 0.5f*s + (i==j ? 0.01f : 0.f);
  } else if (mat == 1) {
    float s = 0.f;
    for (int k = 0; k < 256; ++k) s = fmaf(X[i*256+k], X[j*256+k], s);
    float h1 = s + (i==j ? 0.01f : 0.f);
    ws[WS_Y + idx] = -0.5f*(h1 + Y1[i*128+j] - Y1[j*128+i]);
  } else if (mat == 2) {
    float s = 0.f;
    for (int k = 0; k < 256; ++k) s = fmaf(X[i*256+k], X[(128+j)*256+k], s);
    ws[WS_R + idx] = -s - Chi[i*128+j];
  } else if (mat == 3) {
    if (j == 0) {
      float lam = 0.f;
      for (int k = 0; k < 256; ++k) { float v = X[(128+i)*256+k]; lam = fmaf(v, v, lam); }
      ws[WS_LAM + i] = 0.5f*(lam + 0.01f);
    }
  } else {
    float lam = 0.f, s = 0.f;
    for (int k = 0; k < 256; ++k) {
      float vi = X[(128+i)*256+k];
      lam = fmaf(vi, vi, lam);
      s = fmaf(vi, X[(128+j)*256+k], s);
    }
    lam = 0.5f*(lam + 0.01f);
    ws[WS_D11 + j*128 + i] = (j < i) ? (-s / lam) : 0.f;
  }
}

// K2: Gauss-Jordan inversion of P (SPD), 1 block x 1024 threads.
__global__ __launch_bounds__(1024) void k2_invert(float* __restrict__ ws)
{
  __shared__ float Pls[128*130];
  __shared__ float fcol[128];
  const int t = threadIdx.x;
  for (int idx = t; idx < 16384; idx += 1024) {
    int i = idx >> 7, j = idx & 127;
    Pls[i*130 + j] = ws[WS_P + idx];
  }
  __syncthreads();
  for (int k = 0; k < 128; ++k) {
    float pinv = 1.0f / Pls[k*130+k];
    if (t < 128) fcol[t] = Pls[t*130+k];
    __syncthreads();
    if (t < 128) {
      int j = t;
      if (j == k) Pls[k*130+j] = pinv;
      else        Pls[k*130+j] *= pinv;
    } else if (t < 256) {
      int i = t - 128;
      if (i != k) Pls[i*130+k] = -fcol[i]*pinv;
    }
    __syncthreads();
    for (int idx = t; idx < 16384; idx += 1024) {
      int i = idx >> 7, j = idx & 127;
      if (i != k && j != k) Pls[i*130+j] = fmaf(-fcol[i], Pls[k*130+j], Pls[i*130+j]);
    }
    __syncthreads();
  }
  for (int idx = t; idx < 16384; idx += 1024) {
    int i = idx >> 7, j = idx & 127;
    ws[WS_P + idx] = Pls[i*130+j];
  }
}

// K3: A = Pinv@Y, B1 = Pinv@R.
__global__ __launch_bounds__(256) void k3_solve(float* __restrict__ ws)
{
  const int i = blockIdx.x;
  const int t = threadIdx.x;
  const int j = t & 127;
  const int which = t >> 7;
  const float* Pinv = ws + WS_P;
  const float* Src  = ws + (which ? WS_R : WS_Y);
  float* Dst        = ws + (which ? WS_B1 : WS_A);
  float s = 0.f;
  for (int k = 0; k < 128; ++k) s = fmaf(Pinv[i*128+k], Src[k*128+j], s);
  Dst[i*128+j] = s;
}

// KCVT: pack all GEMM B-operand matrices into bf16 frag arrays + packed diag.
__global__ __launch_bounds__(256) void kcvt(
    const float* __restrict__ Chi, const float* __restrict__ D12,
    const float* __restrict__ B2, const float* __restrict__ C2,
    const float* __restrict__ D21, const float* __restrict__ D22,
    float* __restrict__ ws)
{
  int gid = blockIdx.x * 256 + threadIdx.x;
  ushort* dstb = (ushort*)ws;
  if (gid >= 102400) {               // packed diag tiles [4][32][32]
    int l = gid - 102400;            // 4096
    int t4 = l >> 10, rem = l & 1023, il = rem >> 5, jl = rem & 31;
    float v = ws[WS_D11 + (t4*32 + jl)*128 + (t4*32 + il)];  // D11[t*32+il][t*32+jl]
    dstb[FB_DIAG + l] = f2bf(v);
    return;
  }
  float val; int n, k, KS, dst;
  if (gid < 16384)      { int l = gid;        n=l>>7; k=l&127; KS=4; val = ws[WS_A + l];  dst = FB_A; }
  else if (gid < 32768) { int l = gid-16384;  n=l>>7; k=l&127; KS=4; val = ws[WS_B1 + l]; dst = FB_B1; }
  else if (gid < 49152) { int l = gid-32768;  n=l>>7; k=l&127; KS=4;
                          val = Chi[k*128+n] / ws[WS_LAM + n];        dst = FB_C1; }
  else if (gid < 57344) { int l = gid-49152;  n=l>>6; k=l&63;  KS=2; val = D12[l]; dst = FB_D12; }
  else if (gid < 65536) { int l = gid-57344;  n=l>>6; k=l&63;  KS=2; val = B2[l];  dst = FB_B2; }
  else if (gid < 73728) { int l = gid-65536;  n=l>>7; k=l&127; KS=4; val = C2[l];  dst = FB_C2; }
  else if (gid < 81920) { int l = gid-73728;  n=l>>7; k=l&127; KS=4; val = D21[l]; dst = FB_D21; }
  else if (gid < 86016) { int l = gid-81920;  n=l>>6; k=l&63;  KS=2; val = D22[l]; dst = FB_D22; }
  else                  { int l = gid-86016;  n=l>>7; k=l&127; KS=4;
                          val = ws[WS_D11 + k*128 + n];               dst = FB_D11; }  // D11[n][k]
  dstb[dst + frag_idx(n, k, KS)] = f2bf(val);
}

// ---- K4 LDS layout (bytes) ----
#define LDS_W    0       // w bf16 A-frags [4 m][4 ks][64 lane][8] = 16384
#define LDS_BW   16384   // base bf16 [64][132] ushort = 16896
#define LDS_DIAG 33280   // 4096 ushort = 8192
#define LDS_TOT  41472

// K4: fused forward, 64 batch rows/block, 4 waves, wave g owns rows 16g..16g+15.
// Barrier-free after diag staging: all LDS traffic is wave-local.
__global__ __launch_bounds__(256, 3) void k4_forward(
    const float* __restrict__ xi, const float* __restrict__ u,
    const float* __restrict__ ws,
    float* __restrict__ out)
{
  __shared__ __align__(16) char smem[LDS_TOT];
  ushort* sbw   = (ushort*)(smem + LDS_BW);
  ushort* wfr   = (ushort*)(smem + LDS_W);
  const ushort* sdiag = (const ushort*)(smem + LDS_DIAG);
  const ushort* wsb = (const ushort*)ws;

  const int tid  = threadIdx.x;
  const int lane = tid & 63;
  const int g    = __builtin_amdgcn_readfirstlane(tid >> 6);
  const int row0 = blockIdx.x * 64;

  // stage diag tiles (the only shared LDS data)
  {
    ushort* dst = (ushort*)(smem + LDS_DIAG);
    *(u16x8*)(dst + tid*16)     = *(const u16x8*)(wsb + FB_DIAG + tid*16);
    *(u16x8*)(dst + tid*16 + 8) = *(const u16x8*)(wsb + FB_DIAG + tid*16 + 8);
  }

  // ---- load xi/u A-frags directly global -> registers (bf16) ----
  s16x8 xif[4], uf[2];
  {
    const int r  = row0 + g*16 + (lane & 15);
    const int c0 = (lane >> 4) << 3;
    #pragma unroll
    for (int ks = 0; ks < 4; ++ks) {
      float4 a = *(const float4*)(xi + (size_t)r*128 + ks*32 + c0);
      float4 b = *(const float4*)(xi + (size_t)r*128 + ks*32 + c0 + 4);
      s16x8 f;
      f[0]=(short)f2bf(a.x); f[1]=(short)f2bf(a.y); f[2]=(short)f2bf(a.z); f[3]=(short)f2bf(a.w);
      f[4]=(short)f2bf(b.x); f[5]=(short)f2bf(b.y); f[6]=(short)f2bf(b.z); f[7]=(short)f2bf(b.w);
      xif[ks] = f;
    }
    #pragma unroll
    for (int ks = 0; ks < 2; ++ks) {
      float4 a = *(const float4*)(u + (size_t)r*64 + ks*32 + c0);
      float4 b = *(const float4*)(u + (size_t)r*64 + ks*32 + c0 + 4);
      s16x8 f;
      f[0]=(short)f2bf(a.x); f[1]=(short)f2bf(a.y); f[2]=(short)f2bf(a.z); f[3]=(short)f2bf(a.w);
      f[4]=(short)f2bf(b.x); f[5]=(short)f2bf(b.y); f[6]=(short)f2bf(b.z); f[7]=(short)f2bf(b.w);
      uf[ks] = f;
    }
  }
  __syncthreads();   // diag visible; last barrier in the kernel

  const int rl = (lane >> 4) * 4;   // C/D row base
  const int cl = lane & 15;         // C/D col

  // ---- base = xi@C1^T + u@D12^T (MFMA) -> s_bw bf16 ----
  {
    f32x4 acc[8];
    #pragma unroll
    for (int nt = 0; nt < 8; ++nt) acc[nt] = (f32x4){0.f,0.f,0.f,0.f};
    #pragma unroll
    for (int ks = 0; ks < 4; ++ks)
      #pragma unroll
      for (int nt = 0; nt < 8; ++nt) {
        s16x8 bf = *(const s16x8*)(wsb + FB_C1 + ((((nt*4+ks)<<6) + lane)<<3));
        acc[nt] = MFMA(xif[ks], bf, acc[nt], 0, 0, 0);
      }
    #pragma unroll
    for (int ks = 0; ks < 2; ++ks)
      #pragma unroll
      for (int nt = 0; nt < 8; ++nt) {
        s16x8 bf = *(const s16x8*)(wsb + FB_D12 + ((((nt*2+ks)<<6) + lane)<<3));
        acc[nt] = MFMA(uf[ks], bf, acc[nt], 0, 0, 0);
      }
    #pragma unroll
    for (int nt = 0; nt < 8; ++nt)
      #pragma unroll
      for (int r = 0; r < 4; ++r)
        sbw[(g*16 + rl + r)*132 + nt*16 + cl] = f2bf(acc[nt][r]);
  }

  // ---- recurrence (wave-local): per tile t: MFMA inter-tile + 32 serial steps ----
  {
    const int c  = lane & 3;
    const int rr = g*16 + (lane >> 2);
    const int lane_lo = lane >> 2;           // rr & 15
    #pragma unroll
    for (int t = 0; t < 4; ++t) {
      const int i0 = t*32;
      if (t > 0) {
        f32x4 sig[2];
        sig[0] = (f32x4){0.f,0.f,0.f,0.f};
        sig[1] = (f32x4){0.f,0.f,0.f,0.f};
        for (int ks = 0; ks < t; ++ks) {
          s16x8 a = *(const s16x8*)(wfr + (((g*4 + ks)<<6) + lane)*8);
          #pragma unroll
          for (int q = 0; q < 2; ++q) {
            s16x8 b = *(const s16x8*)(wsb + FB_D11 + (((((2*t+q)*4 + ks)<<6) + lane)<<3));
            sig[q] = MFMA(a, b, sig[q], 0, 0, 0);
          }
        }
        #pragma unroll
        for (int q = 0; q < 2; ++q)
          #pragma unroll
          for (int r = 0; r < 4; ++r) {
            int idx = (g*16 + rl + r)*132 + i0 + q*16 + cl;
            sbw[idx] = f2bf(bf2f(sbw[idx]) + sig[q][r]);
          }
      }
      // preload base (owner-lane layout): lane c holds cols i0+4k+c
      float bse[8];
      #pragma unroll
      for (int k = 0; k < 8; ++k) bse[k] = bf2f(sbw[rr*132 + i0 + 4*k + c]);
      float wq[8];
      #pragma unroll
      for (int k = 0; k < 8; ++k) wq[k] = 0.f;
      const int dbase = t*1024;
      #pragma unroll
      for (int il = 0; il < 32; ++il) {
        float p0 = 0.f;
        const int nf = il >> 2;
        #pragma unroll
        for (int k = 0; k < nf; ++k)
          p0 = fmaf(bf2f(sdiag[dbase + il*32 + 4*k + c]), wq[k], p0);
        if ((il & 3) && c < (il & 3))
          p0 = fmaf(bf2f(sdiag[dbase + il*32 + 4*nf + c]), wq[nf], p0);
        p0 = qreduce(p0);                       // DPP quad reduce
        float v = fast_tanh(bse[il >> 2] + p0); // correct on owner lane
        if (c == (il & 3)) wq[il >> 2] = v;
      }
      // batch-write this tile's w as bf16 A-frags (k_abs = i0+4k+c)
      #pragma unroll
      for (int k = 0; k < 8; ++k) {
        int ka = 4*k + c;                       // within-tile k (i0 mult of 32)
        int lanep = lane_lo + (((ka >> 3) & 3) << 4);
        wfr[((((g*4 + t)<<6) + lanep)<<3) + (ka & 7)] = f2bf(wq[k]);
      }
    }
  }

  // ---- output GEMMs (MFMA): xi@A^T + w@B1^T + u@B2^T ; xi@C2^T + w@D21^T + u@D22^T ----
  f32x4 ax[8], ay[4];
  #pragma unroll
  for (int nt = 0; nt < 8; ++nt) ax[nt] = (f32x4){0.f,0.f,0.f,0.f};
  #pragma unroll
  for (int nt = 0; nt < 4; ++nt) ay[nt] = (f32x4){0.f,0.f,0.f,0.f};

  #pragma unroll
  for (int ks = 0; ks < 4; ++ks) {
    #pragma unroll
    for (int nt = 0; nt < 8; ++nt) {
      s16x8 bf = *(const s16x8*)(wsb + FB_A + ((((nt*4+ks)<<6) + lane)<<3));
      ax[nt] = MFMA(xif[ks], bf, ax[nt], 0, 0, 0);
    }
    #pragma unroll
    for (int nt = 0; nt < 4; ++nt) {
      s16x8 bf = *(const s16x8*)(wsb + FB_C2 + ((((nt*4+ks)<<6) + lane)<<3));
      ay[nt] = MFMA(xif[ks], bf, ay[nt], 0, 0, 0);
    }
  }
  #pragma unroll
  for (int ks = 0; ks < 4; ++ks) {
    s16x8 a = *(const s16x8*)(wfr + (((g*4 + ks)<<6) + lane)*8);
    #pragma unroll
    for (int nt = 0; nt < 8; ++nt) {
      s16x8 bf = *(const s16x8*)(wsb + FB_B1 + ((((nt*4+ks)<<6) + lane)<<3));
      ax[nt] = MFMA(a, bf, ax[nt], 0, 0, 0);
    }
    #pragma unroll
    for (int nt = 0; nt < 4; ++nt) {
      s16x8 bf = *(const s16x8*)(wsb + FB_D21 + ((((nt*4+ks)<<6) + lane)<<3));
      ay[nt] = MFMA(a, bf, ay[nt], 0, 0, 0);
    }
  }
  #pragma unroll
  for (int ks = 0; ks < 2; ++ks) {
    #pragma unroll
    for (int nt = 0; nt < 8; ++nt) {
      s16x8 bf = *(const s16x8*)(wsb + FB_B2 + ((((nt*2+ks)<<6) + lane)<<3));
      ax[nt] = MFMA(uf[ks], bf, ax[nt], 0, 0, 0);
    }
    #pragma unroll
    for (int nt = 0; nt < 4; ++nt) {
      s16x8 bf = *(const s16x8*)(wsb + FB_D22 + ((((nt*2+ks)<<6) + lane)<<3));
      ay[nt] = MFMA(uf[ks], bf, ay[nt], 0, 0, 0);
    }
  }

  // ---- stores (C/D layout: row = 16g + rl + r, col = nt*16 + cl) ----
  #pragma unroll
  for (int nt = 0; nt < 8; ++nt)
    #pragma unroll
    for (int r = 0; r < 4; ++r)
      out[(size_t)(row0 + g*16 + rl + r)*128 + nt*16 + cl] = ax[nt][r];
  const size_t yoff = (size_t)BATCHc * 128;
  #pragma unroll
  for (int nt = 0; nt < 4; ++nt)
    #pragma unroll
    for (int r = 0; r < 4; ++r)
      out[yoff + (size_t)(row0 + g*16 + rl + r)*64 + nt*16 + cl] = ay[nt][r];
}

extern "C" void kernel_launch(void* const* d_in, const int* in_sizes, int n_in,
                              void* d_out, int out_size, void* d_ws, size_t ws_size,
                              hipStream_t stream) {
  // inputs: 0:t 1:xi 2:u 3:Pstar 4:Chi 5:Y1 6:X 7:B2 8:D12 9:C2 10:D21 11:D22
  const float* xi    = (const float*)d_in[1];
  const float* u     = (const float*)d_in[2];
  const float* Pstar = (const float*)d_in[3];
  const float* Chi   = (const float*)d_in[4];
  const float* Y1    = (const float*)d_in[5];
  const float* X     = (const float*)d_in[6];
  const float* B2    = (const float*)d_in[7];
  const float* D12   = (const float*)d_in[8];
  const float* C2    = (const float*)d_in[9];
  const float* D21   = (const float*)d_in[10];
  const float* D22   = (const float*)d_in[11];
  float* out = (float*)d_out;
  float* ws  = (float*)d_ws;   // uses ~435 KB (<= 459 KB proven in earlier rounds)

  k1_params<<<320, 256, 0, stream>>>(Pstar, Chi, Y1, X, ws);
  k2_invert<<<1, 1024, 0, stream>>>(ws);
  k3_solve<<<128, 256, 0, stream>>>(ws);
  kcvt<<<416, 256, 0, stream>>>(Chi, D12, B2, C2, D21, D22, ws);
  k4_forward<<<(BATCHc/64), 256, 0, stream>>>(xi, u, ws, out);
}

// Round 9
// 353.953 us; speedup vs baseline: 13.1703x; 1.3796x over previous
//
#include <hip/hip_runtime.h>
#include <math.h>

// Problem constants
#define BATCHc 200000

// ---- workspace layout ----
// float offsets:
#define WS_P    0        // dead after k3; overlaid by frags in kcvt
#define WS_Y    16384
#define WS_R    32768
#define WS_A    49152
#define WS_B1   65536
#define WS_D11  81920    // D11T fp32: D11T[j*128+i] = D11[i][j]
#define WS_LAM  98304    // 128 floats
// bf16 frag arrays, ushort offsets from (ushort*)ws:
#define FB_A    0        // overlay P/Y/R region (bytes < 172032 < 196608)
#define FB_B1   16384
#define FB_C1   32768
#define FB_D12  49152
#define FB_B2   57344
#define FB_C2   65536
#define FB_D21  73728
#define FB_D22  81920    // ends 86016
#define FB_D11  197120   // float off 98560.. (16384 ushorts, after WS_LAM)
#define FB_DIAG 213504   // 4096 ushorts packed [4][32][32]; ends byte 435200

typedef __attribute__((ext_vector_type(8))) short s16x8;
typedef __attribute__((ext_vector_type(8))) unsigned short u16x8;
typedef __attribute__((ext_vector_type(4))) float f32x4;
#define MFMA __builtin_amdgcn_mfma_f32_16x16x32_bf16

__device__ __forceinline__ float fast_tanh(float x) {
  float e = __expf(2.0f * x);
  return 1.0f - 2.0f / (e + 1.0f);
}
__device__ __forceinline__ ushort f2bf(float f) {
  unsigned int u = __builtin_bit_cast(unsigned int, f);
  u = (u + 0x7FFFu + ((u >> 16) & 1u)) >> 16;
  return (ushort)u;
}
__device__ __forceinline__ float bf2f(ushort h) {
  return __builtin_bit_cast(float, (unsigned int)h << 16);
}
// 4-lane (quad) butterfly reduce via DPP quad_perm — VALU-latency, no LDS
__device__ __forceinline__ float qreduce(float x) {
  int a = __builtin_amdgcn_mov_dpp(__builtin_bit_cast(int, x), 0xB1, 0xF, 0xF, true);
  x += __builtin_bit_cast(float, a);
  int b = __builtin_amdgcn_mov_dpp(__builtin_bit_cast(int, x), 0x4E, 0xF, 0xF, true);
  x += __builtin_bit_cast(float, b);
  return x;
}

// frag index for matrix (N x K) row-major, element (n,k):
__device__ __forceinline__ int frag_idx(int n, int k, int KS) {
  int lane = (n & 15) + (((k >> 3) & 3) << 4);
  return ((((n >> 4) * KS + (k >> 5)) << 6) + lane) * 8 + (k & 7);
}

// K1: P, Y, R, lam, D11T into ws.
__global__ __launch_bounds__(256) void k1_params(
    const float* __restrict__ Pstar, const float* __restrict__ Chi,
    const float* __restrict__ Y1, const float* __restrict__ X,
    float* __restrict__ ws)
{
  int gid = blockIdx.x * 256 + threadIdx.x;
  int mat = gid >> 14;
  int idx = gid & 16383;
  int i = idx >> 7, j = idx & 127;
  if (mat == 0) {
    float s = 0.f;
    for (int k = 0; k < 128; ++k) s = fmaf(Pstar[i*128+k], Pstar[j*128+k], s);
    ws[WS_P + idx] = 0.5f*s + (i==j ? 0.01f : 0.f);
  } else if (mat == 1) {
    float s = 0.f;
    for (int k = 0; k < 256; ++k) s = fmaf(X[i*256+k], X[j*256+k], s);
    float h1 = s + (i==j ? 0.01f : 0.f);
    ws[WS_Y + idx] = -0.5f*(h1 + Y1[i*128+j] - Y1[j*128+i]);
  } else if (mat == 2) {
    float s = 0.f;
    for (int k = 0; k < 256; ++k) s = fmaf(X[i*256+k], X[(128+j)*256+k], s);
    ws[WS_R + idx] = -s - Chi[i*128+j];
  } else if (mat == 3) {
    if (j == 0) {
      float lam = 0.f;
      for (int k = 0; k < 256; ++k) { float v = X[(128+i)*256+k]; lam = fmaf(v, v, lam); }
      ws[WS_LAM + i] = 0.5f*(lam + 0.01f);
    }
  } else {
    float lam = 0.f, s = 0.f;
    for (int k = 0; k < 256; ++k) {
      float vi = X[(128+i)*256+k];
      lam = fmaf(vi, vi, lam);
      s = fmaf(vi, X[(128+j)*256+k], s);
    }
    lam = 0.5f*(lam + 0.01f);
    ws[WS_D11 + j*128 + i] = (j < i) ? (-s / lam) : 0.f;
  }
}

// K2: Gauss-Jordan inversion of P (SPD, no pivoting), 1 block x 512 threads.
// Matrix held in REGISTERS: thread (i = t>>2, jb = (t&3)*32) owns row i,
// cols jb..jb+31. Per iteration: snapshot row k (register dump, static) and
// col k (compare-select extract, static indices) to LDS; barrier; update
// registers from snapshots only (exact scalar-GJ formulas); barrier.
// 2 barriers/iter, no LDS matrix traffic.
__global__ __launch_bounds__(512) void k2_invert(float* __restrict__ ws)
{
  __shared__ __align__(16) float fcol[128];
  __shared__ __align__(16) float frow[128];
  const int t  = threadIdx.x;
  const int i  = t >> 2;
  const int jb = (t & 3) * 32;

  float areg[32];
  #pragma unroll
  for (int c4 = 0; c4 < 8; ++c4) {
    float4 v = *(const float4*)&ws[WS_P + i*128 + jb + c4*4];
    areg[c4*4+0]=v.x; areg[c4*4+1]=v.y; areg[c4*4+2]=v.z; areg[c4*4+3]=v.w;
  }

  for (int k = 0; k < 128; ++k) {
    // ---- snapshot phase (writes LDS from registers, static indices) ----
    if (i == k) {
      #pragma unroll
      for (int c4 = 0; c4 < 8; ++c4) {
        float4 v = {areg[c4*4+0], areg[c4*4+1], areg[c4*4+2], areg[c4*4+3]};
        *(float4*)&frow[jb + c4*4] = v;
      }
    }
    {
      float av = 0.f;
      #pragma unroll
      for (int c = 0; c < 32; ++c) av = (jb + c == k) ? areg[c] : av;
      if ((unsigned)(k - jb) < 32u) fcol[i] = av;
    }
    __syncthreads();

    // ---- update phase (reads snapshots, writes registers only) ----
    const float pinv = 1.0f / fcol[k];
    const bool prow = (i == k);
    const float fp = fcol[i] * pinv;
    float fr[32];
    #pragma unroll
    for (int c4 = 0; c4 < 8; ++c4) {
      float4 v = *(const float4*)&frow[jb + c4*4];
      fr[c4*4+0]=v.x; fr[c4*4+1]=v.y; fr[c4*4+2]=v.z; fr[c4*4+3]=v.w;
    }
    #pragma unroll
    for (int c = 0; c < 32; ++c) {
      float nv = prow ? (fr[c] * pinv) : fmaf(-fp, fr[c], areg[c]);
      areg[c] = (jb + c == k) ? (prow ? pinv : -fp) : nv;
    }
    __syncthreads();
  }

  #pragma unroll
  for (int c4 = 0; c4 < 8; ++c4) {
    float4 v = {areg[c4*4+0], areg[c4*4+1], areg[c4*4+2], areg[c4*4+3]};
    *(float4*)&ws[WS_P + i*128 + jb + c4*4] = v;
  }
}

// K3: A = Pinv@Y, B1 = Pinv@R.
__global__ __launch_bounds__(256) void k3_solve(float* __restrict__ ws)
{
  const int i = blockIdx.x;
  const int t = threadIdx.x;
  const int j = t & 127;
  const int which = t >> 7;
  const float* Pinv = ws + WS_P;
  const float* Src  = ws + (which ? WS_R : WS_Y);
  float* Dst        = ws + (which ? WS_B1 : WS_A);
  float s = 0.f;
  for (int k = 0; k < 128; ++k) s = fmaf(Pinv[i*128+k], Src[k*128+j], s);
  Dst[i*128+j] = s;
}

// KCVT: pack all GEMM B-operand matrices into bf16 frag arrays + packed diag.
__global__ __launch_bounds__(256) void kcvt(
    const float* __restrict__ Chi, const float* __restrict__ D12,
    const float* __restrict__ B2, const float* __restrict__ C2,
    const float* __restrict__ D21, const float* __restrict__ D22,
    float* __restrict__ ws)
{
  int gid = blockIdx.x * 256 + threadIdx.x;
  ushort* dstb = (ushort*)ws;
  if (gid >= 102400) {               // packed diag tiles [4][32][32]
    int l = gid - 102400;            // 4096
    int t4 = l >> 10, rem = l & 1023, il = rem >> 5, jl = rem & 31;
    float v = ws[WS_D11 + (t4*32 + jl)*128 + (t4*32 + il)];  // D11[t*32+il][t*32+jl]
    dstb[FB_DIAG + l] = f2bf(v);
    return;
  }
  float val; int n, k, KS, dst;
  if (gid < 16384)      { int l = gid;        n=l>>7; k=l&127; KS=4; val = ws[WS_A + l];  dst = FB_A; }
  else if (gid < 32768) { int l = gid-16384;  n=l>>7; k=l&127; KS=4; val = ws[WS_B1 + l]; dst = FB_B1; }
  else if (gid < 49152) { int l = gid-32768;  n=l>>7; k=l&127; KS=4;
                          val = Chi[k*128+n] / ws[WS_LAM + n];        dst = FB_C1; }
  else if (gid < 57344) { int l = gid-49152;  n=l>>6; k=l&63;  KS=2; val = D12[l]; dst = FB_D12; }
  else if (gid < 65536) { int l = gid-57344;  n=l>>6; k=l&63;  KS=2; val = B2[l];  dst = FB_B2; }
  else if (gid < 73728) { int l = gid-65536;  n=l>>7; k=l&127; KS=4; val = C2[l];  dst = FB_C2; }
  else if (gid < 81920) { int l = gid-73728;  n=l>>7; k=l&127; KS=4; val = D21[l]; dst = FB_D21; }
  else if (gid < 86016) { int l = gid-81920;  n=l>>6; k=l&63;  KS=2; val = D22[l]; dst = FB_D22; }
  else                  { int l = gid-86016;  n=l>>7; k=l&127; KS=4;
                          val = ws[WS_D11 + k*128 + n];               dst = FB_D11; }  // D11[n][k]
  dstb[dst + frag_idx(n, k, KS)] = f2bf(val);
}

// ---- K4 LDS layout (bytes) ----
#define LDS_W    0       // w bf16 A-frags [4 m][4 ks][64 lane][8] = 16384
#define LDS_BW   16384   // base bf16 [64][132] ushort = 16896
#define LDS_DIAG 33280   // 4096 ushort = 8192
#define LDS_TOT  41472

// K4: fused forward, 64 batch rows/block, 4 waves, wave g owns rows 16g..16g+15.
// Barrier-free after diag staging: all LDS traffic is wave-local.
__global__ __launch_bounds__(256, 3) void k4_forward(
    const float* __restrict__ xi, const float* __restrict__ u,
    const float* __restrict__ ws,
    float* __restrict__ out)
{
  __shared__ __align__(16) char smem[LDS_TOT];
  ushort* sbw   = (ushort*)(smem + LDS_BW);
  ushort* wfr   = (ushort*)(smem + LDS_W);
  const ushort* sdiag = (const ushort*)(smem + LDS_DIAG);
  const ushort* wsb = (const ushort*)ws;

  const int tid  = threadIdx.x;
  const int lane = tid & 63;
  const int g    = __builtin_amdgcn_readfirstlane(tid >> 6);
  const int row0 = blockIdx.x * 64;

  // stage diag tiles (the only shared LDS data)
  {
    ushort* dst = (ushort*)(smem + LDS_DIAG);
    *(u16x8*)(dst + tid*16)     = *(const u16x8*)(wsb + FB_DIAG + tid*16);
    *(u16x8*)(dst + tid*16 + 8) = *(const u16x8*)(wsb + FB_DIAG + tid*16 + 8);
  }

  // ---- load xi/u A-frags directly global -> registers (bf16) ----
  s16x8 xif[4], uf[2];
  {
    const int r  = row0 + g*16 + (lane & 15);
    const int c0 = (lane >> 4) << 3;
    #pragma unroll
    for (int ks = 0; ks < 4; ++ks) {
      float4 a = *(const float4*)(xi + (size_t)r*128 + ks*32 + c0);
      float4 b = *(const float4*)(xi + (size_t)r*128 + ks*32 + c0 + 4);
      s16x8 f;
      f[0]=(short)f2bf(a.x); f[1]=(short)f2bf(a.y); f[2]=(short)f2bf(a.z); f[3]=(short)f2bf(a.w);
      f[4]=(short)f2bf(b.x); f[5]=(short)f2bf(b.y); f[6]=(short)f2bf(b.z); f[7]=(short)f2bf(b.w);
      xif[ks] = f;
    }
    #pragma unroll
    for (int ks = 0; ks < 2; ++ks) {
      float4 a = *(const float4*)(u + (size_t)r*64 + ks*32 + c0);
      float4 b = *(const float4*)(u + (size_t)r*64 + ks*32 + c0 + 4);
      s16x8 f;
      f[0]=(short)f2bf(a.x); f[1]=(short)f2bf(a.y); f[2]=(short)f2bf(a.z); f[3]=(short)f2bf(a.w);
      f[4]=(short)f2bf(b.x); f[5]=(short)f2bf(b.y); f[6]=(short)f2bf(b.z); f[7]=(short)f2bf(b.w);
      uf[ks] = f;
    }
  }
  __syncthreads();   // diag visible; last barrier in the kernel

  const int rl = (lane >> 4) * 4;   // C/D row base
  const int cl = lane & 15;         // C/D col

  // ---- base = xi@C1^T + u@D12^T (MFMA) -> s_bw bf16 ----
  {
    f32x4 acc[8];
    #pragma unroll
    for (int nt = 0; nt < 8; ++nt) acc[nt] = (f32x4){0.f,0.f,0.f,0.f};
    #pragma unroll
    for (int ks = 0; ks < 4; ++ks)
      #pragma unroll
      for (int nt = 0; nt < 8; ++nt) {
        s16x8 bf = *(const s16x8*)(wsb + FB_C1 + ((((nt*4+ks)<<6) + lane)<<3));
        acc[nt] = MFMA(xif[ks], bf, acc[nt], 0, 0, 0);
      }
    #pragma unroll
    for (int ks = 0; ks < 2; ++ks)
      #pragma unroll
      for (int nt = 0; nt < 8; ++nt) {
        s16x8 bf = *(const s16x8*)(wsb + FB_D12 + ((((nt*2+ks)<<6) + lane)<<3));
        acc[nt] = MFMA(uf[ks], bf, acc[nt], 0, 0, 0);
      }
    #pragma unroll
    for (int nt = 0; nt < 8; ++nt)
      #pragma unroll
      for (int r = 0; r < 4; ++r)
        sbw[(g*16 + rl + r)*132 + nt*16 + cl] = f2bf(acc[nt][r]);
  }

  // ---- recurrence (wave-local): per tile t: MFMA inter-tile + 32 serial steps ----
  {
    const int c  = lane & 3;
    const int rr = g*16 + (lane >> 2);
    const int lane_lo = lane >> 2;           // rr & 15
    #pragma unroll
    for (int t = 0; t < 4; ++t) {
      const int i0 = t*32;
      if (t > 0) {
        f32x4 sig[2];
        sig[0] = (f32x4){0.f,0.f,0.f,0.f};
        sig[1] = (f32x4){0.f,0.f,0.f,0.f};
        for (int ks = 0; ks < t; ++ks) {
          s16x8 a = *(const s16x8*)(wfr + (((g*4 + ks)<<6) + lane)*8);
          #pragma unroll
          for (int q = 0; q < 2; ++q) {
            s16x8 b = *(const s16x8*)(wsb + FB_D11 + (((((2*t+q)*4 + ks)<<6) + lane)<<3));
            sig[q] = MFMA(a, b, sig[q], 0, 0, 0);
          }
        }
        #pragma unroll
        for (int q = 0; q < 2; ++q)
          #pragma unroll
          for (int r = 0; r < 4; ++r) {
            int idx = (g*16 + rl + r)*132 + i0 + q*16 + cl;
            sbw[idx] = f2bf(bf2f(sbw[idx]) + sig[q][r]);
          }
      }
      // preload base (owner-lane layout): lane c holds cols i0+4k+c
      float bse[8];
      #pragma unroll
      for (int k = 0; k < 8; ++k) bse[k] = bf2f(sbw[rr*132 + i0 + 4*k + c]);
      float wq[8];
      #pragma unroll
      for (int k = 0; k < 8; ++k) wq[k] = 0.f;
      const int dbase = t*1024;
      #pragma unroll
      for (int il = 0; il < 32; ++il) {
        float p0 = 0.f;
        const int nf = il >> 2;
        #pragma unroll
        for (int k = 0; k < nf; ++k)
          p0 = fmaf(bf2f(sdiag[dbase + il*32 + 4*k + c]), wq[k], p0);
        if ((il & 3) && c < (il & 3))
          p0 = fmaf(bf2f(sdiag[dbase + il*32 + 4*nf + c]), wq[nf], p0);
        p0 = qreduce(p0);                       // DPP quad reduce
        float v = fast_tanh(bse[il >> 2] + p0); // correct on owner lane
        if (c == (il & 3)) wq[il >> 2] = v;
      }
      // batch-write this tile's w as bf16 A-frags (k_abs = i0+4k+c)
      #pragma unroll
      for (int k = 0; k < 8; ++k) {
        int ka = 4*k + c;                       // within-tile k (i0 mult of 32)
        int lanep = lane_lo + (((ka >> 3) & 3) << 4);
        wfr[((((g*4 + t)<<6) + lanep)<<3) + (ka & 7)] = f2bf(wq[k]);
      }
    }
  }

  // ---- output GEMMs (MFMA): xi@A^T + w@B1^T + u@B2^T ; xi@C2^T + w@D21^T + u@D22^T ----
  f32x4 ax[8], ay[4];
  #pragma unroll
  for (int nt = 0; nt < 8; ++nt) ax[nt] = (f32x4){0.f,0.f,0.f,0.f};
  #pragma unroll
  for (int nt = 0; nt < 4; ++nt) ay[nt] = (f32x4){0.f,0.f,0.f,0.f};

  #pragma unroll
  for (int ks = 0; ks < 4; ++ks) {
    #pragma unroll
    for (int nt = 0; nt < 8; ++nt) {
      s16x8 bf = *(const s16x8*)(wsb + FB_A + ((((nt*4+ks)<<6) + lane)<<3));
      ax[nt] = MFMA(xif[ks], bf, ax[nt], 0, 0, 0);
    }
    #pragma unroll
    for (int nt = 0; nt < 4; ++nt) {
      s16x8 bf = *(const s16x8*)(wsb + FB_C2 + ((((nt*4+ks)<<6) + lane)<<3));
      ay[nt] = MFMA(xif[ks], bf, ay[nt], 0, 0, 0);
    }
  }
  #pragma unroll
  for (int ks = 0; ks < 4; ++ks) {
    s16x8 a = *(const s16x8*)(wfr + (((g*4 + ks)<<6) + lane)*8);
    #pragma unroll
    for (int nt = 0; nt < 8; ++nt) {
      s16x8 bf = *(const s16x8*)(wsb + FB_B1 + ((((nt*4+ks)<<6) + lane)<<3));
      ax[nt] = MFMA(a, bf, ax[nt], 0, 0, 0);
    }
    #pragma unroll
    for (int nt = 0; nt < 4; ++nt) {
      s16x8 bf = *(const s16x8*)(wsb + FB_D21 + ((((nt*4+ks)<<6) + lane)<<3));
      ay[nt] = MFMA(a, bf, ay[nt], 0, 0, 0);
    }
  }
  #pragma unroll
  for (int ks = 0; ks < 2; ++ks) {
    #pragma unroll
    for (int nt = 0; nt < 8; ++nt) {
      s16x8 bf = *(const s16x8*)(wsb + FB_B2 + ((((nt*2+ks)<<6) + lane)<<3));
      ax[nt] = MFMA(uf[ks], bf, ax[nt], 0, 0, 0);
    }
    #pragma unroll
    for (int nt = 0; nt < 4; ++nt) {
      s16x8 bf = *(const s16x8*)(wsb + FB_D22 + ((((nt*2+ks)<<6) + lane)<<3));
      ay[nt] = MFMA(uf[ks], bf, ay[nt], 0, 0, 0);
    }
  }

  // ---- stores (C/D layout: row = 16g + rl + r, col = nt*16 + cl) ----
  #pragma unroll
  for (int nt = 0; nt < 8; ++nt)
    #pragma unroll
    for (int r = 0; r < 4; ++r)
      out[(size_t)(row0 + g*16 + rl + r)*128 + nt*16 + cl] = ax[nt][r];
  const size_t yoff = (size_t)BATCHc * 128;
  #pragma unroll
  for (int nt = 0; nt < 4; ++nt)
    #pragma unroll
    for (int r = 0; r < 4; ++r)
      out[yoff + (size_t)(row0 + g*16 + rl + r)*64 + nt*16 + cl] = ay[nt][r];
}

extern "C" void kernel_launch(void* const* d_in, const int* in_sizes, int n_in,
                              void* d_out, int out_size, void* d_ws, size_t ws_size,
                              hipStream_t stream) {
  // inputs: 0:t 1:xi 2:u 3:Pstar 4:Chi 5:Y1 6:X 7:B2 8:D12 9:C2 10:D21 11:D22
  const float* xi    = (const float*)d_in[1];
  const float* u     = (const float*)d_in[2];
  const float* Pstar = (const float*)d_in[3];
  const float* Chi   = (const float*)d_in[4];
  const float* Y1    = (const float*)d_in[5];
  const float* X     = (const float*)d_in[6];
  const float* B2    = (const float*)d_in[7];
  const float* D12   = (const float*)d_in[8];
  const float* C2    = (const float*)d_in[9];
  const float* D21   = (const float*)d_in[10];
  const float* D22   = (const float*)d_in[11];
  float* out = (float*)d_out;
  float* ws  = (float*)d_ws;   // uses ~435 KB (<= 459 KB proven in earlier rounds)

  k1_params<<<320, 256, 0, stream>>>(Pstar, Chi, Y1, X, ws);
  k2_invert<<<1, 512, 0, stream>>>(ws);
  k3_solve<<<128, 256, 0, stream>>>(ws);
  kcvt<<<416, 256, 0, stream>>>(Chi, D12, B2, C2, D21, D22, ws);
  k4_forward<<<(BATCHc/64), 256, 0, stream>>>(xi, u, ws, out);
}